// Round 9
// baseline (285.450 us; speedup 1.0000x reference)
//
#include <hip/hip_runtime.h>
#include <stdint.h>

#define JX 2048
#define JQ 128
#define DEN 256
#define NB 64

typedef __attribute__((ext_vector_type(4))) float f32x4;
typedef __attribute__((ext_vector_type(8))) short short8;
typedef _Float16 f16x8 __attribute__((ext_vector_type(8)));

__device__ __forceinline__ unsigned short f2bf(float f) {
  union { float f; unsigned int u; } v; v.f = f;
  unsigned int r = v.u + 0x7FFFu + ((v.u >> 16) & 1u);
  return (unsigned short)(r >> 16);
}
__device__ __forceinline__ float bf2f(unsigned short b) {
  union { float f; unsigned int u; } v; v.u = ((unsigned int)b) << 16;
  return v.f;
}
__device__ __forceinline__ unsigned pkh2(float a, float b) {
  union { _Float16 h[2]; unsigned u; } v;
  v.h[0] = (_Float16)a; v.h[1] = (_Float16)b; return v.u;
}

// hi/lo bf16 split of 8 f32 via v_cvt_pk_bf16_f32 (RNE, == f2bf bit pattern)
__device__ __forceinline__ void cvt_hilo8(const f32x4 x0, const f32x4 x1,
                                          short8* hi, short8* lo) {
  union { unsigned u[4]; short8 s; } H, L;
  float f[8];
#pragma unroll
  for (int j = 0; j < 4; ++j) { f[j] = x0[j]; f[4 + j] = x1[j]; }
#pragma unroll
  for (int k = 0; k < 4; ++k) {
    unsigned hk;
    asm("v_cvt_pk_bf16_f32 %0, %1, %2" : "=v"(hk) : "v"(f[2 * k]), "v"(f[2 * k + 1]));
    H.u[k] = hk;
    union { unsigned u; float fl; } h0, h1;
    h0.u = hk << 16;
    h1.u = hk & 0xffff0000u;
    float d0 = f[2 * k] - h0.fl;
    float d1 = f[2 * k + 1] - h1.fl;
    unsigned lk;
    asm("v_cvt_pk_bf16_f32 %0, %1, %2" : "=v"(lk) : "v"(d0), "v"(d1));
    L.u[k] = lk;
  }
  *hi = H.s;
  *lo = L.s;
}

// K0: u fp32 [n][128][256] -> u_hi,u_lo bf16 row-major + uT f16 [n][256][128]
__global__ __launch_bounds__(256) void k0_prep_u(const float* __restrict__ u,
    unsigned short* __restrict__ u_hi, unsigned short* __restrict__ u_lo,
    _Float16* __restrict__ uT16) {
  int n = blockIdx.y, dc = blockIdx.x, t = threadIdx.x;
  const float* un = u + (size_t)n * JQ * DEN;
  unsigned short* uhn = u_hi + (size_t)n * JQ * DEN;
  unsigned short* uln = u_lo + (size_t)n * JQ * DEN;
  __shared__ float lds[JQ * 65];
  for (int i = t; i < JQ * 64; i += 256) {
    int q = i >> 6, dl = i & 63;
    int idx = q * DEN + dc * 64 + dl;
    float f = un[idx];
    unsigned short hi = f2bf(f);
    uhn[idx] = hi;
    uln[idx] = f2bf(f - bf2f(hi));
    lds[q * 65 + dl] = f;
  }
  __syncthreads();
  _Float16* utn = uT16 + (size_t)n * DEN * JQ;
  for (int i = t; i < 64 * JQ; i += 256) {
    int dl = i >> 7, q = i & 127;
    utn[(size_t)(dc * 64 + dl) * JQ + q] = (_Float16)lds[q * 65 + dl];
  }
}

// K1: de-staged swapped-operand attention. Block (n, xb) = 128 x-rows,
// 4 waves x 32 rows. All u/uT operand fragments read DIRECTLY from global
// (L2-hot: 16 same-n blocks per XCD). Only 2 barriers per block.
// QK: s^T = MFMA(A=u hi/lo bf16, B=h hi/lo from regs). Softmax lane-local.
// p packed f16 to per-wave LDS arena. PV: A=uT f16 direct, B=p from arena.
// Epilogue: prefetched h regs, NT f32x4 stores q1,q2,q3 + fused h_tilde partials.
__global__ __launch_bounds__(256, 4) void k1_attn(
    const float* __restrict__ h, const unsigned short* __restrict__ u_hi,
    const unsigned short* __restrict__ u_lo, const _Float16* __restrict__ uT16,
    float* __restrict__ out, float* __restrict__ partM,
    float* __restrict__ partE, float* __restrict__ partV) {
  __shared__ __align__(16) unsigned char PW[4][8192];  // per-wave p arena
  __shared__ float vbuf[4][256];
  __shared__ float redM[4], redE[4];

  const int n = blockIdx.x, xb = blockIdx.y;
  const int tid = threadIdx.x;
  const int wave = tid >> 6, lane = tid & 63;
  const int l15 = lane & 15, lq = lane >> 4;
  const int rowbase = xb * 128 + wave * 32;

  const unsigned short* uh = u_hi + (size_t)n * JQ * DEN;
  const unsigned short* ul = u_lo + (size_t)n * JQ * DEN;
  const _Float16* uT = uT16 + (size_t)n * DEN * JQ;
  const float* hr0 = h + (size_t)(n * JX + rowbase + l15) * DEN;
  const float* hr1 = hr0 + (size_t)16 * DEN;

  f32x4 acc[2][8];
#pragma unroll
  for (int t = 0; t < 2; ++t)
#pragma unroll
    for (int q = 0; q < 8; ++q) acc[t][q] = (f32x4)(0.f);

  // ---- QK: 8 k-blocks of 32 cols, operands direct from global ----
  f32x4 hn[2][2];
  hn[0][0] = *(const f32x4*)(hr0 + lq * 8);
  hn[0][1] = *(const f32x4*)(hr0 + lq * 8 + 4);
  hn[1][0] = *(const f32x4*)(hr1 + lq * 8);
  hn[1][1] = *(const f32x4*)(hr1 + lq * 8 + 4);
#pragma unroll
  for (int c = 0; c < 8; ++c) {
    f32x4 hc[2][2];
#pragma unroll
    for (int t = 0; t < 2; ++t) { hc[t][0] = hn[t][0]; hc[t][1] = hn[t][1]; }
    if (c < 7) {
      hn[0][0] = *(const f32x4*)(hr0 + (c + 1) * 32 + lq * 8);
      hn[0][1] = *(const f32x4*)(hr0 + (c + 1) * 32 + lq * 8 + 4);
      hn[1][0] = *(const f32x4*)(hr1 + (c + 1) * 32 + lq * 8);
      hn[1][1] = *(const f32x4*)(hr1 + (c + 1) * 32 + lq * 8 + 4);
    }
    short8 bhi[2], blo[2];
#pragma unroll
    for (int t = 0; t < 2; ++t) cvt_hilo8(hc[t][0], hc[t][1], &bhi[t], &blo[t]);
    const int kb = c * 32 + lq * 8;
#pragma unroll
    for (int qt = 0; qt < 8; ++qt) {
      const int qrow = qt * 16 + l15;
      const short8 uhf = *(const short8*)(uh + (size_t)qrow * DEN + kb);
      const short8 ulf = *(const short8*)(ul + (size_t)qrow * DEN + kb);
      acc[0][qt] = __builtin_amdgcn_mfma_f32_16x16x32_bf16(ulf, bhi[0], acc[0][qt], 0, 0, 0);
      acc[0][qt] = __builtin_amdgcn_mfma_f32_16x16x32_bf16(uhf, blo[0], acc[0][qt], 0, 0, 0);
      acc[0][qt] = __builtin_amdgcn_mfma_f32_16x16x32_bf16(uhf, bhi[0], acc[0][qt], 0, 0, 0);
      acc[1][qt] = __builtin_amdgcn_mfma_f32_16x16x32_bf16(ulf, bhi[1], acc[1][qt], 0, 0, 0);
      acc[1][qt] = __builtin_amdgcn_mfma_f32_16x16x32_bf16(uhf, blo[1], acc[1][qt], 0, 0, 0);
      acc[1][qt] = __builtin_amdgcn_mfma_f32_16x16x32_bf16(uhf, bhi[1], acc[1][qt], 0, 0, 0);
    }
  }

  // ---- softmax over q (x = l15 lane-local, replicated across lq) ----
  float mvt[2], rinv[2];
#pragma unroll
  for (int t = 0; t < 2; ++t) {
    float mv = acc[t][0][0];
#pragma unroll
    for (int qt = 0; qt < 8; ++qt)
#pragma unroll
      for (int r = 0; r < 4; ++r) mv = fmaxf(mv, acc[t][qt][r]);
    mv = fmaxf(mv, __shfl_xor(mv, 16));
    mv = fmaxf(mv, __shfl_xor(mv, 32));
    float s = 0.f;
#pragma unroll
    for (int qt = 0; qt < 8; ++qt)
#pragma unroll
      for (int r = 0; r < 4; ++r) {
        float p = __expf(acc[t][qt][r] - mv);
        acc[t][qt][r] = p;
        s += p;
      }
    s += __shfl_xor(s, 16);
    s += __shfl_xor(s, 32);
    mvt[t] = mv;
    rinv[t] = 1.f / s;
  }

  float wmax = fmaxf(mvt[0], mvt[1]);
  wmax = fmaxf(wmax, __shfl_xor(wmax, 1));
  wmax = fmaxf(wmax, __shfl_xor(wmax, 2));
  wmax = fmaxf(wmax, __shfl_xor(wmax, 4));
  wmax = fmaxf(wmax, __shfl_xor(wmax, 8));
  if (lane == 0) redM[wave] = wmax;
  __syncthreads();  // barrier #1: redM visible
  const float Mblk = fmaxf(fmaxf(redM[0], redM[1]), fmaxf(redM[2], redM[3]));
  const float w0 = __expf(mvt[0] - Mblk);
  const float w1 = __expf(mvt[1] - Mblk);
  float es = w0 + w1;
  es += __shfl_xor(es, 1);
  es += __shfl_xor(es, 2);
  es += __shfl_xor(es, 4);
  es += __shfl_xor(es, 8);
  if (lane == 0) redE[wave] = es;

  // ---- pack p (unnormalized, joint-t) into per-wave arena (wave-private) ----
  char* pw = (char*)PW[wave];
  const int swz = (l15 & 7) << 4;
#pragma unroll
  for (int t = 0; t < 2; ++t)
#pragma unroll
    for (int qt = 0; qt < 8; ++qt) {
      union { unsigned u2[2]; uint2 u; } pk;
      pk.u2[0] = pkh2(acc[t][qt][0], acc[t][qt][1]);
      pk.u2[1] = pkh2(acc[t][qt][2], acc[t][qt][3]);
      *(uint2*)(pw + (t * 16 + l15) * 256 + ((32 * qt + 8 * lq) ^ swz)) = pk.u;
    }

  // prefetch h regs for epilogue chunk 0
  f32x4 hpre[2][4];
#pragma unroll
  for (int t = 0; t < 2; ++t)
#pragma unroll
    for (int dt = 0; dt < 4; ++dt)
      hpre[t][dt] = *(const f32x4*)(h + (size_t)(n * JX + rowbase + t * 16 + l15) * DEN +
                                    dt * 16 + lq * 4);

  // ---- PV + epilogue: 4 chunks of 64 d-cols, uT direct from global ----
#pragma unroll
  for (int c = 0; c < 4; ++c) {
    f32x4 vacc[2][4];
#pragma unroll
    for (int t = 0; t < 2; ++t)
#pragma unroll
      for (int dt = 0; dt < 4; ++dt) vacc[t][dt] = (f32x4)(0.f);
#pragma unroll
    for (int ks = 0; ks < 4; ++ks) {
      f16x8 pf[2];
#pragma unroll
      for (int t = 0; t < 2; ++t)
        pf[t] = *(const f16x8*)(pw + (t * 16 + l15) * 256 + ((64 * ks + 16 * lq) ^ swz));
#pragma unroll
      for (int dt = 0; dt < 4; ++dt) {
        const int drow = c * 64 + dt * 16 + l15;
        const f16x8 Af = *(const f16x8*)(uT + (size_t)drow * JQ + ks * 32 + lq * 8);
        vacc[0][dt] = __builtin_amdgcn_mfma_f32_16x16x32_f16(Af, pf[0], vacc[0][dt], 0, 0, 0);
        vacc[1][dt] = __builtin_amdgcn_mfma_f32_16x16x32_f16(Af, pf[1], vacc[1][dt], 0, 0, 0);
      }
    }

    // epilogue: rows x=rowbase+t*16+l15, cols c*64+dt*16+lq*4..+3
    f32x4 pacc[4];
#pragma unroll
    for (int dt = 0; dt < 4; ++dt) pacc[dt] = (f32x4)(0.f);
#pragma unroll
    for (int t = 0; t < 2; ++t) {
      const float wt = t ? w1 : w0;
#pragma unroll
      for (int dt = 0; dt < 4; ++dt) {
        int colbase = c * 64 + dt * 16 + lq * 4;
        size_t xg = (size_t)(n * JX + rowbase + t * 16 + l15);
        f32x4 hv = hpre[t][dt];
        f32x4 ut = vacc[t][dt] * rinv[t];
        float* op = out + xg * 1024 + colbase;
        __builtin_nontemporal_store(hv, (f32x4*)op);
        __builtin_nontemporal_store(ut, (f32x4*)(op + 256));
        f32x4 hu = hv * ut;
        __builtin_nontemporal_store(hu, (f32x4*)(op + 512));
        pacc[dt] += hv * wt;
      }
    }
    if (c < 3) {  // prefetch h for chunk c+1 (after last hpre use)
#pragma unroll
      for (int t = 0; t < 2; ++t)
#pragma unroll
        for (int dt = 0; dt < 4; ++dt)
          hpre[t][dt] = *(const f32x4*)(h + (size_t)(n * JX + rowbase + t * 16 + l15) * DEN +
                                        (c + 1) * 64 + dt * 16 + lq * 4);
    }
#pragma unroll
    for (int dt = 0; dt < 4; ++dt) {
#pragma unroll
      for (int sh = 1; sh <= 8; sh <<= 1) {
#pragma unroll
        for (int j = 0; j < 4; ++j) pacc[dt][j] += __shfl_xor(pacc[dt][j], sh);
      }
      if (l15 == 0)
        *(f32x4*)(&vbuf[wave][c * 64 + dt * 16 + lq * 4]) = pacc[dt];
    }
  }

  __syncthreads();  // barrier #2: vbuf + redE visible
  float v = vbuf[0][tid] + vbuf[1][tid] + vbuf[2][tid] + vbuf[3][tid];
  partV[((size_t)(n * 16 + xb)) * 256 + tid] = v;
  if (tid == 0) {
    partM[n * 16 + xb] = Mblk;
    partE[n * 16 + xb] = redE[0] + redE[1] + redE[2] + redE[3];
  }
}

// K3: merge block partials (online-softmax weighted), write quarter 4.
__global__ __launch_bounds__(256) void k3_quarter4(const float* __restrict__ h,
    const float* __restrict__ partM, const float* __restrict__ partE,
    const float* __restrict__ partV, float* __restrict__ out) {
  int n = blockIdx.y, xc = blockIdx.x, t = threadIdx.x;
  __shared__ float sm[16], se[16];
  __shared__ float ht[DEN];
  if (t < 16) { sm[t] = partM[n * 16 + t]; se[t] = partE[n * 16 + t]; }
  __syncthreads();
  float M = sm[0];
#pragma unroll
  for (int c = 1; c < 16; ++c) M = fmaxf(M, sm[c]);
  float den = 0.f, s = 0.f;
#pragma unroll
  for (int c = 0; c < 16; ++c) {
    float fc = __expf(sm[c] - M);
    den += fc * se[c];
    s += fc * partV[((size_t)(n * 16 + c)) * 256 + t];
  }
  ht[t] = s / den;
  __syncthreads();
  int wave = t >> 6, c4 = t & 63;
  f32x4 htv = *(const f32x4*)(ht + c4 * 4);
#pragma unroll
  for (int i = 0; i < 8; ++i) {
    int row = xc * 32 + i * 4 + wave;
    f32x4 hv = *(const f32x4*)(h + (size_t)(n * JX + row) * DEN + c4 * 4);
    f32x4 hh = hv * htv;
    __builtin_nontemporal_store(hh,
        (f32x4*)(out + (size_t)(n * JX + row) * 1024 + 768 + c4 * 4));
  }
}

extern "C" void kernel_launch(void* const* d_in, const int* in_sizes, int n_in,
                              void* d_out, int out_size, void* d_ws, size_t ws_size,
                              hipStream_t stream) {
  const float* h = (const float*)d_in[0];
  const float* u = (const float*)d_in[1];
  float* out = (float*)d_out;
  char* ws = (char*)d_ws;

  size_t off = 0;
  unsigned short* u_hi = (unsigned short*)(ws + off); off += (size_t)NB * JQ * DEN * 2;
  unsigned short* u_lo = (unsigned short*)(ws + off); off += (size_t)NB * JQ * DEN * 2;
  _Float16* uT16 = (_Float16*)(ws + off); off += (size_t)NB * DEN * JQ * 2;
  float* partM = (float*)(ws + off); off += (size_t)NB * 16 * 4;
  float* partE = (float*)(ws + off); off += (size_t)NB * 16 * 4;
  float* partV = (float*)(ws + off); off += (size_t)NB * 16 * DEN * 4;

  hipLaunchKernelGGL(k0_prep_u, dim3(4, NB), dim3(256), 0, stream, u, u_hi, u_lo, uT16);
  hipLaunchKernelGGL(k1_attn, dim3(NB, JX / 128), dim3(256), 0, stream,
                     h, u_hi, u_lo, uT16, out, partM, partE, partV);
  hipLaunchKernelGGL(k3_quarter4, dim3(64, NB), dim3(256), 0, stream,
                     h, partM, partE, partV, out);
}

// Round 10
// 253.232 us; speedup vs baseline: 1.1272x; 1.1272x over previous
//
#include <hip/hip_runtime.h>
#include <stdint.h>

#define JX 2048
#define JQ 128
#define DEN 256
#define NB 64

typedef __attribute__((ext_vector_type(4))) float f32x4;
typedef __attribute__((ext_vector_type(8))) short short8;
typedef _Float16 f16x8 __attribute__((ext_vector_type(8)));

typedef __attribute__((address_space(1))) const unsigned int as1_uint;
typedef __attribute__((address_space(3))) unsigned int as3_uint;

__device__ __forceinline__ unsigned short f2bf(float f) {
  union { float f; unsigned int u; } v; v.f = f;
  unsigned int r = v.u + 0x7FFFu + ((v.u >> 16) & 1u);
  return (unsigned short)(r >> 16);
}
__device__ __forceinline__ float bf2f(unsigned short b) {
  union { float f; unsigned int u; } v; v.u = ((unsigned int)b) << 16;
  return v.f;
}
__device__ __forceinline__ void gload_lds16(const void* src, void* dst) {
  __builtin_amdgcn_global_load_lds((as1_uint*)src, (as3_uint*)dst, 16, 0, 0);
}
__device__ __forceinline__ unsigned pkh2(float a, float b) {
  union { _Float16 h[2]; unsigned u; } v;
  v.h[0] = (_Float16)a; v.h[1] = (_Float16)b; return v.u;
}

// hi/lo bf16 split of 8 f32 via v_cvt_pk_bf16_f32 (RNE, == f2bf bit pattern)
__device__ __forceinline__ void cvt_hilo8(const f32x4 x0, const f32x4 x1,
                                          short8* hi, short8* lo) {
  union { unsigned u[4]; short8 s; } H, L;
  float f[8];
#pragma unroll
  for (int j = 0; j < 4; ++j) { f[j] = x0[j]; f[4 + j] = x1[j]; }
#pragma unroll
  for (int k = 0; k < 4; ++k) {
    unsigned hk;
    asm("v_cvt_pk_bf16_f32 %0, %1, %2" : "=v"(hk) : "v"(f[2 * k]), "v"(f[2 * k + 1]));
    H.u[k] = hk;
    union { unsigned u; float fl; } h0, h1;
    h0.u = hk << 16;
    h1.u = hk & 0xffff0000u;
    float d0 = f[2 * k] - h0.fl;
    float d1 = f[2 * k + 1] - h1.fl;
    unsigned lk;
    asm("v_cvt_pk_bf16_f32 %0, %1, %2" : "=v"(lk) : "v"(d0), "v"(d1));
    L.u[k] = lk;
  }
  *hi = H.s;
  *lo = L.s;
}

// K0: u fp32 [n][128][256] -> u_hi,u_lo bf16 row-major + uT f16 [n][256][128]
__global__ __launch_bounds__(256) void k0_prep_u(const float* __restrict__ u,
    unsigned short* __restrict__ u_hi, unsigned short* __restrict__ u_lo,
    _Float16* __restrict__ uT16) {
  int n = blockIdx.y, dc = blockIdx.x, t = threadIdx.x;
  const float* un = u + (size_t)n * JQ * DEN;
  unsigned short* uhn = u_hi + (size_t)n * JQ * DEN;
  unsigned short* uln = u_lo + (size_t)n * JQ * DEN;
  __shared__ float lds[JQ * 65];
  for (int i = t; i < JQ * 64; i += 256) {
    int q = i >> 6, dl = i & 63;
    int idx = q * DEN + dc * 64 + dl;
    float f = un[idx];
    unsigned short hi = f2bf(f);
    uhn[idx] = hi;
    uln[idx] = f2bf(f - bf2f(hi));
    lds[q * 65 + dl] = f;
  }
  __syncthreads();
  _Float16* utn = uT16 + (size_t)n * DEN * JQ;
  for (int i = t; i < 64 * JQ; i += 256) {
    int dl = i >> 7, q = i & 127;
    utn[(size_t)(dc * 64 + dl) * JQ + q] = (_Float16)lds[q * 65 + dl];
  }
}

// K1: swapped-operand attention, counted-vmcnt pipelined barriers, NORMAL stores.
__global__ __launch_bounds__(256, 3) void k1_attn(
    const float* __restrict__ h, const unsigned short* __restrict__ u_hi,
    const unsigned short* __restrict__ u_lo, const _Float16* __restrict__ uT16,
    float* __restrict__ out, float* __restrict__ partM,
    float* __restrict__ partE, float* __restrict__ partV) {
  __shared__ __align__(16) unsigned char SA[32768];  // QK dbuf -> p-arena
  __shared__ __align__(16) unsigned char SB[16384];  // uT chunk (single buf)
  __shared__ float vbuf[4][256];
  __shared__ float redM[4], redE[4];

  const int n = blockIdx.x, xb = blockIdx.y;
  const int tid = threadIdx.x;
  const int wave = tid >> 6, lane = tid & 63;
  const int l15 = lane & 15, lq = lane >> 4;
  const int rowbase = xb * 128 + wave * 32;

  const char* uhB = (const char*)(u_hi + (size_t)n * JQ * DEN);
  const char* ulB = (const char*)(u_lo + (size_t)n * JQ * DEN);
  const char* uTB = (const char*)(uT16 + (size_t)n * DEN * JQ);
  const float* hr0 = h + (size_t)(n * JX + rowbase + l15) * DEN;
  const float* hr1 = hr0 + (size_t)16 * DEN;

#define STAGE_QK(BUF, C)                                                     \
  {                                                                          \
    _Pragma("unroll")                                                        \
    for (int rr = 0; rr < 4; ++rr) {                                         \
      int L = rr * 4096 + tid * 16;                                          \
      int row = L >> 7;                                                      \
      int sb = ((L >> 4) & 7) ^ (row & 7);                                   \
      const char* s = (sb & 4) ? ulB : uhB;                                  \
      gload_lds16(s + (size_t)row * 512 + (C) * 64 + (sb & 3) * 16,          \
                  &SA[(BUF) * 16384 + L]);                                   \
    }                                                                        \
  }

  f32x4 acc[2][8];
#pragma unroll
  for (int t = 0; t < 2; ++t)
#pragma unroll
    for (int q = 0; q < 8; ++q) acc[t][q] = (f32x4)(0.f);

  STAGE_QK(0, 0);
  f32x4 hn[2][2];
  hn[0][0] = *(const f32x4*)(hr0 + lq * 8);
  hn[0][1] = *(const f32x4*)(hr0 + lq * 8 + 4);
  hn[1][0] = *(const f32x4*)(hr1 + lq * 8);
  hn[1][1] = *(const f32x4*)(hr1 + lq * 8 + 4);
  // wait only the 4 stage loads (oldest); h loads stay in flight
  asm volatile("s_waitcnt vmcnt(4)" ::: "memory");
  __builtin_amdgcn_s_barrier();
  __builtin_amdgcn_sched_barrier(0);

#pragma unroll
  for (int c = 0; c < 8; ++c) {
    const int b = c & 1;
    if (c < 7) STAGE_QK(b ^ 1, c + 1);
    f32x4 hc[2][2];
#pragma unroll
    for (int t = 0; t < 2; ++t) { hc[t][0] = hn[t][0]; hc[t][1] = hn[t][1]; }
    if (c < 7) {
      hn[0][0] = *(const f32x4*)(hr0 + (c + 1) * 32 + lq * 8);
      hn[0][1] = *(const f32x4*)(hr0 + (c + 1) * 32 + lq * 8 + 4);
      hn[1][0] = *(const f32x4*)(hr1 + (c + 1) * 32 + lq * 8);
      hn[1][1] = *(const f32x4*)(hr1 + (c + 1) * 32 + lq * 8 + 4);
    }
    short8 bhi[2], blo[2];
#pragma unroll
    for (int t = 0; t < 2; ++t) cvt_hilo8(hc[t][0], hc[t][1], &bhi[t], &blo[t]);
    __builtin_amdgcn_s_setprio(1);
#pragma unroll
    for (int qt = 0; qt < 8; ++qt) {
      int row = qt * 16 + l15;
      const short8 uhf = *(const short8*)(&SA[b * 16384 + row * 128 + ((lq ^ (row & 7)) << 4)]);
      const short8 ulf = *(const short8*)(&SA[b * 16384 + row * 128 + (((4 | lq) ^ (row & 7)) << 4)]);
      acc[0][qt] = __builtin_amdgcn_mfma_f32_16x16x32_bf16(ulf, bhi[0], acc[0][qt], 0, 0, 0);
      acc[0][qt] = __builtin_amdgcn_mfma_f32_16x16x32_bf16(uhf, blo[0], acc[0][qt], 0, 0, 0);
      acc[0][qt] = __builtin_amdgcn_mfma_f32_16x16x32_bf16(uhf, bhi[0], acc[0][qt], 0, 0, 0);
      acc[1][qt] = __builtin_amdgcn_mfma_f32_16x16x32_bf16(ulf, bhi[1], acc[1][qt], 0, 0, 0);
      acc[1][qt] = __builtin_amdgcn_mfma_f32_16x16x32_bf16(uhf, blo[1], acc[1][qt], 0, 0, 0);
      acc[1][qt] = __builtin_amdgcn_mfma_f32_16x16x32_bf16(uhf, bhi[1], acc[1][qt], 0, 0, 0);
    }
    __builtin_amdgcn_s_setprio(0);
    if (c < 7) {
      asm volatile("s_waitcnt vmcnt(4)" ::: "memory");
      __builtin_amdgcn_s_barrier();
      __builtin_amdgcn_sched_barrier(0);
    }
  }

  // stage uT chunk 0 directly (drained at the redM __syncthreads below)
  {
#pragma unroll
    for (int rr = 0; rr < 4; ++rr) {
      int L = rr * 4096 + tid * 16;
      int row = L >> 8;
      int cb = ((L >> 4) & 15) ^ (row & 7);
      gload_lds16(uTB + (size_t)(row)*256 + cb * 16, &SB[L]);
    }
  }

  // softmax over q (x = l15 lane-local, replicated across lq)
  float mvt[2], rinv[2];
#pragma unroll
  for (int t = 0; t < 2; ++t) {
    float mv = acc[t][0][0];
#pragma unroll
    for (int qt = 0; qt < 8; ++qt)
#pragma unroll
      for (int r = 0; r < 4; ++r) mv = fmaxf(mv, acc[t][qt][r]);
    mv = fmaxf(mv, __shfl_xor(mv, 16));
    mv = fmaxf(mv, __shfl_xor(mv, 32));
    float s = 0.f;
#pragma unroll
    for (int qt = 0; qt < 8; ++qt)
#pragma unroll
      for (int r = 0; r < 4; ++r) {
        float p = __expf(acc[t][qt][r] - mv);
        acc[t][qt][r] = p;
        s += p;
      }
    s += __shfl_xor(s, 16);
    s += __shfl_xor(s, 32);
    mvt[t] = mv;
    rinv[t] = 1.f / s;
  }

  float wmax = fmaxf(mvt[0], mvt[1]);
  wmax = fmaxf(wmax, __shfl_xor(wmax, 1));
  wmax = fmaxf(wmax, __shfl_xor(wmax, 2));
  wmax = fmaxf(wmax, __shfl_xor(wmax, 4));
  wmax = fmaxf(wmax, __shfl_xor(wmax, 8));
  if (lane == 0) redM[wave] = wmax;
  __syncthreads();  // redM visible; SB chunk 0 drained; SA safe to reuse
  const float Mblk = fmaxf(fmaxf(redM[0], redM[1]), fmaxf(redM[2], redM[3]));
  const float w0 = __expf(mvt[0] - Mblk);
  const float w1 = __expf(mvt[1] - Mblk);
  float es = w0 + w1;
  es += __shfl_xor(es, 1);
  es += __shfl_xor(es, 2);
  es += __shfl_xor(es, 4);
  es += __shfl_xor(es, 8);
  if (lane == 0) redE[wave] = es;

  // pack p (unnormalized, joint-t) into per-wave arena in SA
  char* pw = (char*)SA + wave * 8192;
  const int swz = (l15 & 7) << 4;
#pragma unroll
  for (int t = 0; t < 2; ++t)
#pragma unroll
    for (int qt = 0; qt < 8; ++qt) {
      union { unsigned u2[2]; uint2 u; } pk;
      pk.u2[0] = pkh2(acc[t][qt][0], acc[t][qt][1]);
      pk.u2[1] = pkh2(acc[t][qt][2], acc[t][qt][3]);
      *(uint2*)(pw + (t * 16 + l15) * 256 + ((32 * qt + 8 * lq) ^ swz)) = pk.u;
    }

  // prefetch: h regs for epilogue chunk 0, uT regs for chunk 1
  f32x4 hpre[2][4];
#pragma unroll
  for (int t = 0; t < 2; ++t)
#pragma unroll
    for (int dt = 0; dt < 4; ++dt)
      hpre[t][dt] = *(const f32x4*)(h + (size_t)(n * JX + rowbase + t * 16 + l15) * DEN +
                                    dt * 16 + lq * 4);
  f32x4 sbreg[4];
#pragma unroll
  for (int rr = 0; rr < 4; ++rr) {
    int L = rr * 4096 + tid * 16;
    int row = L >> 8;
    int cb = ((L >> 4) & 15) ^ (row & 7);
    sbreg[rr] = *(const f32x4*)(uTB + (size_t)(64 + row) * 256 + cb * 16);
  }

  // PV + epilogue: 4 chunks of 64 d-cols
#pragma unroll
  for (int c = 0; c < 4; ++c) {
    f32x4 vacc[2][4];
#pragma unroll
    for (int t = 0; t < 2; ++t)
#pragma unroll
      for (int dt = 0; dt < 4; ++dt) vacc[t][dt] = (f32x4)(0.f);
    __builtin_amdgcn_s_setprio(1);
#pragma unroll
    for (int ks = 0; ks < 4; ++ks) {
      f16x8 pf[2];
#pragma unroll
      for (int t = 0; t < 2; ++t)
        pf[t] = *(const f16x8*)(pw + (t * 16 + l15) * 256 + ((64 * ks + 16 * lq) ^ swz));
#pragma unroll
      for (int dt = 0; dt < 4; ++dt) {
        int row = dt * 16 + l15;
        const f16x8 Af = *(const f16x8*)(&SB[row * 256 + (((4 * ks + lq) ^ (row & 7)) << 4)]);
        vacc[0][dt] = __builtin_amdgcn_mfma_f32_16x16x32_f16(Af, pf[0], vacc[0][dt], 0, 0, 0);
        vacc[1][dt] = __builtin_amdgcn_mfma_f32_16x16x32_f16(Af, pf[1], vacc[1][dt], 0, 0, 0);
      }
    }
    __builtin_amdgcn_s_setprio(0);
    if (c < 3) {
      asm volatile("" ::: "memory");
      __builtin_amdgcn_s_barrier();
      __builtin_amdgcn_sched_barrier(0);
#pragma unroll
      for (int rr = 0; rr < 4; ++rr)
        *(f32x4*)(&SB[rr * 4096 + tid * 16]) = sbreg[rr];
      if (c < 2) {
#pragma unroll
        for (int rr = 0; rr < 4; ++rr) {
          int L = rr * 4096 + tid * 16;
          int row = L >> 8;
          int cb = ((L >> 4) & 15) ^ (row & 7);
          sbreg[rr] = *(const f32x4*)(uTB + (size_t)((c + 2) * 64 + row) * 256 + cb * 16);
        }
      }
    }

    // epilogue: rows x=rowbase+t*16+l15, cols c*64+dt*16+lq*4..+3 (NORMAL stores)
    f32x4 pacc[4];
#pragma unroll
    for (int dt = 0; dt < 4; ++dt) pacc[dt] = (f32x4)(0.f);
#pragma unroll
    for (int t = 0; t < 2; ++t) {
      const float wt = t ? w1 : w0;
#pragma unroll
      for (int dt = 0; dt < 4; ++dt) {
        int colbase = c * 64 + dt * 16 + lq * 4;
        size_t xg = (size_t)(n * JX + rowbase + t * 16 + l15);
        f32x4 hv = hpre[t][dt];
        f32x4 ut = vacc[t][dt] * rinv[t];
        float* op = out + xg * 1024 + colbase;
        *(f32x4*)op = hv;
        *(f32x4*)(op + 256) = ut;
        f32x4 hu = hv * ut;
        *(f32x4*)(op + 512) = hu;
        pacc[dt] += hv * wt;
      }
    }
    if (c < 3) {  // prefetch h for chunk c+1 (after last hpre use)
#pragma unroll
      for (int t = 0; t < 2; ++t)
#pragma unroll
        for (int dt = 0; dt < 4; ++dt)
          hpre[t][dt] = *(const f32x4*)(h + (size_t)(n * JX + rowbase + t * 16 + l15) * DEN +
                                        (c + 1) * 64 + dt * 16 + lq * 4);
    }
#pragma unroll
    for (int dt = 0; dt < 4; ++dt) {
#pragma unroll
      for (int sh = 1; sh <= 8; sh <<= 1) {
#pragma unroll
        for (int j = 0; j < 4; ++j) pacc[dt][j] += __shfl_xor(pacc[dt][j], sh);
      }
      if (l15 == 0)
        *(f32x4*)(&vbuf[wave][c * 64 + dt * 16 + lq * 4]) = pacc[dt];
    }
    if (c < 3) {
      asm volatile("s_waitcnt lgkmcnt(0)" ::: "memory");
      __builtin_amdgcn_s_barrier();
      __builtin_amdgcn_sched_barrier(0);
    }
  }

  __syncthreads();
  float v = vbuf[0][tid] + vbuf[1][tid] + vbuf[2][tid] + vbuf[3][tid];
  partV[((size_t)(n * 16 + xb)) * 256 + tid] = v;
  if (tid == 0) {
    partM[n * 16 + xb] = Mblk;
    partE[n * 16 + xb] = redE[0] + redE[1] + redE[2] + redE[3];
  }
#undef STAGE_QK
}

// K3: merge block partials (online-softmax weighted), write quarter 4 (NORMAL stores).
__global__ __launch_bounds__(256) void k3_quarter4(const float* __restrict__ h,
    const float* __restrict__ partM, const float* __restrict__ partE,
    const float* __restrict__ partV, float* __restrict__ out) {
  int n = blockIdx.y, xc = blockIdx.x, t = threadIdx.x;
  __shared__ float sm[16], se[16];
  __shared__ float ht[DEN];
  if (t < 16) { sm[t] = partM[n * 16 + t]; se[t] = partE[n * 16 + t]; }
  __syncthreads();
  float M = sm[0];
#pragma unroll
  for (int c = 1; c < 16; ++c) M = fmaxf(M, sm[c]);
  float den = 0.f, s = 0.f;
#pragma unroll
  for (int c = 0; c < 16; ++c) {
    float fc = __expf(sm[c] - M);
    den += fc * se[c];
    s += fc * partV[((size_t)(n * 16 + c)) * 256 + t];
  }
  ht[t] = s / den;
  __syncthreads();
  int wave = t >> 6, c4 = t & 63;
  f32x4 htv = *(const f32x4*)(ht + c4 * 4);
#pragma unroll
  for (int i = 0; i < 8; ++i) {
    int row = xc * 32 + i * 4 + wave;
    f32x4 hv = *(const f32x4*)(h + (size_t)(n * JX + row) * DEN + c4 * 4);
    f32x4 hh = hv * htv;
    *(f32x4*)(out + (size_t)(n * JX + row) * 1024 + 768 + c4 * 4) = hh;
  }
}

extern "C" void kernel_launch(void* const* d_in, const int* in_sizes, int n_in,
                              void* d_out, int out_size, void* d_ws, size_t ws_size,
                              hipStream_t stream) {
  const float* h = (const float*)d_in[0];
  const float* u = (const float*)d_in[1];
  float* out = (float*)d_out;
  char* ws = (char*)d_ws;

  size_t off = 0;
  unsigned short* u_hi = (unsigned short*)(ws + off); off += (size_t)NB * JQ * DEN * 2;
  unsigned short* u_lo = (unsigned short*)(ws + off); off += (size_t)NB * JQ * DEN * 2;
  _Float16* uT16 = (_Float16*)(ws + off); off += (size_t)NB * DEN * JQ * 2;
  float* partM = (float*)(ws + off); off += (size_t)NB * 16 * 4;
  float* partE = (float*)(ws + off); off += (size_t)NB * 16 * 4;
  float* partV = (float*)(ws + off); off += (size_t)NB * 16 * DEN * 4;

  hipLaunchKernelGGL(k0_prep_u, dim3(4, NB), dim3(256), 0, stream, u, u_hi, u_lo, uT16);
  hipLaunchKernelGGL(k1_attn, dim3(NB, JX / 128), dim3(256), 0, stream,
                     h, u_hi, u_lo, uT16, out, partM, partE, partV);
  hipLaunchKernelGGL(k3_quarter4, dim3(64, NB), dim3(256), 0, stream,
                     h, partM, partE, partV, out);
}

// Round 11
// 219.408 us; speedup vs baseline: 1.3010x; 1.1542x over previous
//
#include <hip/hip_runtime.h>
#include <stdint.h>

#define JX 2048
#define JQ 128
#define DEN 256
#define NB 64

typedef __attribute__((ext_vector_type(4))) float f32x4;
typedef __attribute__((ext_vector_type(8))) short short8;
typedef _Float16 f16x8 __attribute__((ext_vector_type(8)));

typedef __attribute__((address_space(1))) const unsigned int as1_uint;
typedef __attribute__((address_space(3))) unsigned int as3_uint;

__device__ __forceinline__ unsigned short f2bf(float f) {
  union { float f; unsigned int u; } v; v.f = f;
  unsigned int r = v.u + 0x7FFFu + ((v.u >> 16) & 1u);
  return (unsigned short)(r >> 16);
}
__device__ __forceinline__ float bf2f(unsigned short b) {
  union { float f; unsigned int u; } v; v.u = ((unsigned int)b) << 16;
  return v.f;
}
__device__ __forceinline__ void gload_lds16(const void* src, void* dst) {
  __builtin_amdgcn_global_load_lds((as1_uint*)src, (as3_uint*)dst, 16, 0, 0);
}
__device__ __forceinline__ unsigned pkh2(float a, float b) {
  union { _Float16 h[2]; unsigned u; } v;
  v.h[0] = (_Float16)a; v.h[1] = (_Float16)b; return v.u;
}

// hi/lo bf16 split of 8 f32 via v_cvt_pk_bf16_f32 (RNE, == f2bf bit pattern)
__device__ __forceinline__ void cvt_hilo8(const f32x4 x0, const f32x4 x1,
                                          short8* hi, short8* lo) {
  union { unsigned u[4]; short8 s; } H, L;
  float f[8];
#pragma unroll
  for (int j = 0; j < 4; ++j) { f[j] = x0[j]; f[4 + j] = x1[j]; }
#pragma unroll
  for (int k = 0; k < 4; ++k) {
    unsigned hk;
    asm("v_cvt_pk_bf16_f32 %0, %1, %2" : "=v"(hk) : "v"(f[2 * k]), "v"(f[2 * k + 1]));
    H.u[k] = hk;
    union { unsigned u; float fl; } h0, h1;
    h0.u = hk << 16;
    h1.u = hk & 0xffff0000u;
    float d0 = f[2 * k] - h0.fl;
    float d1 = f[2 * k + 1] - h1.fl;
    unsigned lk;
    asm("v_cvt_pk_bf16_f32 %0, %1, %2" : "=v"(lk) : "v"(d0), "v"(d1));
    L.u[k] = lk;
  }
  *hi = H.s;
  *lo = L.s;
}

// K0: u fp32 [n][128][256] -> u_hi,u_lo bf16 row-major + uT f16 [n][256][128]
__global__ __launch_bounds__(256) void k0_prep_u(const float* __restrict__ u,
    unsigned short* __restrict__ u_hi, unsigned short* __restrict__ u_lo,
    _Float16* __restrict__ uT16) {
  int n = blockIdx.y, dc = blockIdx.x, t = threadIdx.x;
  const float* un = u + (size_t)n * JQ * DEN;
  unsigned short* uhn = u_hi + (size_t)n * JQ * DEN;
  unsigned short* uln = u_lo + (size_t)n * JQ * DEN;
  __shared__ float lds[JQ * 65];
  for (int i = t; i < JQ * 64; i += 256) {
    int q = i >> 6, dl = i & 63;
    int idx = q * DEN + dc * 64 + dl;
    float f = un[idx];
    unsigned short hi = f2bf(f);
    uhn[idx] = hi;
    uln[idx] = f2bf(f - bf2f(hi));
    lds[q * 65 + dl] = f;
  }
  __syncthreads();
  _Float16* utn = uT16 + (size_t)n * DEN * JQ;
  for (int i = t; i < 64 * JQ; i += 256) {
    int dl = i >> 7, q = i & 127;
    utn[(size_t)(dc * 64 + dl) * JQ + q] = (_Float16)lds[q * 65 + dl];
  }
}

// K1: swapped-operand attention, counted-vmcnt barriers, NT stores in
// quarter-major order (4 adjacent 64B segments per row per quarter).
__global__ __launch_bounds__(256, 3) void k1_attn(
    const float* __restrict__ h, const unsigned short* __restrict__ u_hi,
    const unsigned short* __restrict__ u_lo, const _Float16* __restrict__ uT16,
    float* __restrict__ out, float* __restrict__ partM,
    float* __restrict__ partE, float* __restrict__ partV) {
  __shared__ __align__(16) unsigned char SA[32768];  // QK dbuf -> p-arena
  __shared__ __align__(16) unsigned char SB[16384];  // uT chunk (single buf)
  __shared__ float vbuf[4][256];
  __shared__ float redM[4], redE[4];

  const int n = blockIdx.x, xb = blockIdx.y;
  const int tid = threadIdx.x;
  const int wave = tid >> 6, lane = tid & 63;
  const int l15 = lane & 15, lq = lane >> 4;
  const int rowbase = xb * 128 + wave * 32;

  const char* uhB = (const char*)(u_hi + (size_t)n * JQ * DEN);
  const char* ulB = (const char*)(u_lo + (size_t)n * JQ * DEN);
  const char* uTB = (const char*)(uT16 + (size_t)n * DEN * JQ);
  const float* hr0 = h + (size_t)(n * JX + rowbase + l15) * DEN;
  const float* hr1 = hr0 + (size_t)16 * DEN;

#define STAGE_QK(BUF, C)                                                     \
  {                                                                          \
    _Pragma("unroll")                                                        \
    for (int rr = 0; rr < 4; ++rr) {                                         \
      int L = rr * 4096 + tid * 16;                                          \
      int row = L >> 7;                                                      \
      int sb = ((L >> 4) & 7) ^ (row & 7);                                   \
      const char* s = (sb & 4) ? ulB : uhB;                                  \
      gload_lds16(s + (size_t)row * 512 + (C) * 64 + (sb & 3) * 16,          \
                  &SA[(BUF) * 16384 + L]);                                   \
    }                                                                        \
  }

  f32x4 acc[2][8];
#pragma unroll
  for (int t = 0; t < 2; ++t)
#pragma unroll
    for (int q = 0; q < 8; ++q) acc[t][q] = (f32x4)(0.f);

  STAGE_QK(0, 0);
  f32x4 hn[2][2];
  hn[0][0] = *(const f32x4*)(hr0 + lq * 8);
  hn[0][1] = *(const f32x4*)(hr0 + lq * 8 + 4);
  hn[1][0] = *(const f32x4*)(hr1 + lq * 8);
  hn[1][1] = *(const f32x4*)(hr1 + lq * 8 + 4);
  asm volatile("s_waitcnt vmcnt(4)" ::: "memory");
  __builtin_amdgcn_s_barrier();
  __builtin_amdgcn_sched_barrier(0);

#pragma unroll
  for (int c = 0; c < 8; ++c) {
    const int b = c & 1;
    if (c < 7) STAGE_QK(b ^ 1, c + 1);
    f32x4 hc[2][2];
#pragma unroll
    for (int t = 0; t < 2; ++t) { hc[t][0] = hn[t][0]; hc[t][1] = hn[t][1]; }
    if (c < 7) {
      hn[0][0] = *(const f32x4*)(hr0 + (c + 1) * 32 + lq * 8);
      hn[0][1] = *(const f32x4*)(hr0 + (c + 1) * 32 + lq * 8 + 4);
      hn[1][0] = *(const f32x4*)(hr1 + (c + 1) * 32 + lq * 8);
      hn[1][1] = *(const f32x4*)(hr1 + (c + 1) * 32 + lq * 8 + 4);
    }
    short8 bhi[2], blo[2];
#pragma unroll
    for (int t = 0; t < 2; ++t) cvt_hilo8(hc[t][0], hc[t][1], &bhi[t], &blo[t]);
    __builtin_amdgcn_s_setprio(1);
#pragma unroll
    for (int qt = 0; qt < 8; ++qt) {
      int row = qt * 16 + l15;
      const short8 uhf = *(const short8*)(&SA[b * 16384 + row * 128 + ((lq ^ (row & 7)) << 4)]);
      const short8 ulf = *(const short8*)(&SA[b * 16384 + row * 128 + (((4 | lq) ^ (row & 7)) << 4)]);
      acc[0][qt] = __builtin_amdgcn_mfma_f32_16x16x32_bf16(ulf, bhi[0], acc[0][qt], 0, 0, 0);
      acc[0][qt] = __builtin_amdgcn_mfma_f32_16x16x32_bf16(uhf, blo[0], acc[0][qt], 0, 0, 0);
      acc[0][qt] = __builtin_amdgcn_mfma_f32_16x16x32_bf16(uhf, bhi[0], acc[0][qt], 0, 0, 0);
      acc[1][qt] = __builtin_amdgcn_mfma_f32_16x16x32_bf16(ulf, bhi[1], acc[1][qt], 0, 0, 0);
      acc[1][qt] = __builtin_amdgcn_mfma_f32_16x16x32_bf16(uhf, blo[1], acc[1][qt], 0, 0, 0);
      acc[1][qt] = __builtin_amdgcn_mfma_f32_16x16x32_bf16(uhf, bhi[1], acc[1][qt], 0, 0, 0);
    }
    __builtin_amdgcn_s_setprio(0);
    if (c < 7) {
      asm volatile("s_waitcnt vmcnt(4)" ::: "memory");
      __builtin_amdgcn_s_barrier();
      __builtin_amdgcn_sched_barrier(0);
    }
  }

  // stage uT chunk 0 directly (drained at the redM __syncthreads below)
  {
#pragma unroll
    for (int rr = 0; rr < 4; ++rr) {
      int L = rr * 4096 + tid * 16;
      int row = L >> 8;
      int cb = ((L >> 4) & 15) ^ (row & 7);
      gload_lds16(uTB + (size_t)(row)*256 + cb * 16, &SB[L]);
    }
  }

  // softmax over q (x = l15 lane-local, replicated across lq)
  float mvt[2], rinv[2];
#pragma unroll
  for (int t = 0; t < 2; ++t) {
    float mv = acc[t][0][0];
#pragma unroll
    for (int qt = 0; qt < 8; ++qt)
#pragma unroll
      for (int r = 0; r < 4; ++r) mv = fmaxf(mv, acc[t][qt][r]);
    mv = fmaxf(mv, __shfl_xor(mv, 16));
    mv = fmaxf(mv, __shfl_xor(mv, 32));
    float s = 0.f;
#pragma unroll
    for (int qt = 0; qt < 8; ++qt)
#pragma unroll
      for (int r = 0; r < 4; ++r) {
        float p = __expf(acc[t][qt][r] - mv);
        acc[t][qt][r] = p;
        s += p;
      }
    s += __shfl_xor(s, 16);
    s += __shfl_xor(s, 32);
    mvt[t] = mv;
    rinv[t] = 1.f / s;
  }

  float wmax = fmaxf(mvt[0], mvt[1]);
  wmax = fmaxf(wmax, __shfl_xor(wmax, 1));
  wmax = fmaxf(wmax, __shfl_xor(wmax, 2));
  wmax = fmaxf(wmax, __shfl_xor(wmax, 4));
  wmax = fmaxf(wmax, __shfl_xor(wmax, 8));
  if (lane == 0) redM[wave] = wmax;
  __syncthreads();  // redM visible; SB chunk 0 drained; SA safe to reuse
  const float Mblk = fmaxf(fmaxf(redM[0], redM[1]), fmaxf(redM[2], redM[3]));
  const float w0 = __expf(mvt[0] - Mblk);
  const float w1 = __expf(mvt[1] - Mblk);
  float es = w0 + w1;
  es += __shfl_xor(es, 1);
  es += __shfl_xor(es, 2);
  es += __shfl_xor(es, 4);
  es += __shfl_xor(es, 8);
  if (lane == 0) redE[wave] = es;

  // pack p (unnormalized, joint-t) into per-wave arena in SA
  char* pw = (char*)SA + wave * 8192;
  const int swz = (l15 & 7) << 4;
#pragma unroll
  for (int t = 0; t < 2; ++t)
#pragma unroll
    for (int qt = 0; qt < 8; ++qt) {
      union { unsigned u2[2]; uint2 u; } pk;
      pk.u2[0] = pkh2(acc[t][qt][0], acc[t][qt][1]);
      pk.u2[1] = pkh2(acc[t][qt][2], acc[t][qt][3]);
      *(uint2*)(pw + (t * 16 + l15) * 256 + ((32 * qt + 8 * lq) ^ swz)) = pk.u;
    }

  // prefetch: h regs for epilogue chunk 0, uT regs for chunk 1
  f32x4 hpre[2][4];
#pragma unroll
  for (int t = 0; t < 2; ++t)
#pragma unroll
    for (int dt = 0; dt < 4; ++dt)
      hpre[t][dt] = *(const f32x4*)(h + (size_t)(n * JX + rowbase + t * 16 + l15) * DEN +
                                    dt * 16 + lq * 4);
  f32x4 sbreg[4];
#pragma unroll
  for (int rr = 0; rr < 4; ++rr) {
    int L = rr * 4096 + tid * 16;
    int row = L >> 8;
    int cb = ((L >> 4) & 15) ^ (row & 7);
    sbreg[rr] = *(const f32x4*)(uTB + (size_t)(64 + row) * 256 + cb * 16);
  }

  // PV + epilogue: 4 chunks of 64 d-cols
#pragma unroll
  for (int c = 0; c < 4; ++c) {
    f32x4 vacc[2][4];
#pragma unroll
    for (int t = 0; t < 2; ++t)
#pragma unroll
      for (int dt = 0; dt < 4; ++dt) vacc[t][dt] = (f32x4)(0.f);
    __builtin_amdgcn_s_setprio(1);
#pragma unroll
    for (int ks = 0; ks < 4; ++ks) {
      f16x8 pf[2];
#pragma unroll
      for (int t = 0; t < 2; ++t)
        pf[t] = *(const f16x8*)(pw + (t * 16 + l15) * 256 + ((64 * ks + 16 * lq) ^ swz));
#pragma unroll
      for (int dt = 0; dt < 4; ++dt) {
        int row = dt * 16 + l15;
        const f16x8 Af = *(const f16x8*)(&SB[row * 256 + (((4 * ks + lq) ^ (row & 7)) << 4)]);
        vacc[0][dt] = __builtin_amdgcn_mfma_f32_16x16x32_f16(Af, pf[0], vacc[0][dt], 0, 0, 0);
        vacc[1][dt] = __builtin_amdgcn_mfma_f32_16x16x32_f16(Af, pf[1], vacc[1][dt], 0, 0, 0);
      }
    }
    __builtin_amdgcn_s_setprio(0);
    if (c < 3) {
      asm volatile("" ::: "memory");
      __builtin_amdgcn_s_barrier();
      __builtin_amdgcn_sched_barrier(0);
#pragma unroll
      for (int rr = 0; rr < 4; ++rr)
        *(f32x4*)(&SB[rr * 4096 + tid * 16]) = sbreg[rr];
      if (c < 2) {
#pragma unroll
        for (int rr = 0; rr < 4; ++rr) {
          int L = rr * 4096 + tid * 16;
          int row = L >> 8;
          int cb = ((L >> 4) & 15) ^ (row & 7);
          sbreg[rr] = *(const f32x4*)(uTB + (size_t)((c + 2) * 64 + row) * 256 + cb * 16);
        }
      }
    }

    // ---- epilogue, quarter-major store order (NT) ----
    // rows x=rowbase+t*16+l15; cols c*64+dt*16+lq*4..+3; per quarter the 4 dt
    // segments (adjacent 64B) issue back-to-back -> full 128B lines assemble fast.
    f32x4 pacc[4];
#pragma unroll
    for (int dt = 0; dt < 4; ++dt) pacc[dt] = (f32x4)(0.f);
#pragma unroll
    for (int t = 0; t < 2; ++t) {
      const float wt = t ? w1 : w0;
      size_t xg = (size_t)(n * JX + rowbase + t * 16 + l15);
      float* ob = out + xg * 1024 + c * 64 + lq * 4;
      // q1: h
#pragma unroll
      for (int dt = 0; dt < 4; ++dt)
        __builtin_nontemporal_store(hpre[t][dt], (f32x4*)(ob + dt * 16));
      // q2: u~
#pragma unroll
      for (int dt = 0; dt < 4; ++dt)
        __builtin_nontemporal_store(vacc[t][dt] * rinv[t], (f32x4*)(ob + 256 + dt * 16));
      // q3: h*u~ (+ h_tilde partial accumulation)
#pragma unroll
      for (int dt = 0; dt < 4; ++dt) {
        f32x4 hv = hpre[t][dt];
        __builtin_nontemporal_store(hv * (vacc[t][dt] * rinv[t]),
                                    (f32x4*)(ob + 512 + dt * 16));
        pacc[dt] += hv * wt;
      }
    }
    if (c < 3) {  // prefetch h for chunk c+1 (after last hpre use)
#pragma unroll
      for (int t = 0; t < 2; ++t)
#pragma unroll
        for (int dt = 0; dt < 4; ++dt)
          hpre[t][dt] = *(const f32x4*)(h + (size_t)(n * JX + rowbase + t * 16 + l15) * DEN +
                                        (c + 1) * 64 + dt * 16 + lq * 4);
    }
#pragma unroll
    for (int dt = 0; dt < 4; ++dt) {
#pragma unroll
      for (int sh = 1; sh <= 8; sh <<= 1) {
#pragma unroll
        for (int j = 0; j < 4; ++j) pacc[dt][j] += __shfl_xor(pacc[dt][j], sh);
      }
      if (l15 == 0)
        *(f32x4*)(&vbuf[wave][c * 64 + dt * 16 + lq * 4]) = pacc[dt];
    }
    if (c < 3) {
      asm volatile("s_waitcnt lgkmcnt(0)" ::: "memory");
      __builtin_amdgcn_s_barrier();
      __builtin_amdgcn_sched_barrier(0);
    }
  }

  __syncthreads();
  float v = vbuf[0][tid] + vbuf[1][tid] + vbuf[2][tid] + vbuf[3][tid];
  partV[((size_t)(n * 16 + xb)) * 256 + tid] = v;
  if (tid == 0) {
    partM[n * 16 + xb] = Mblk;
    partE[n * 16 + xb] = redE[0] + redE[1] + redE[2] + redE[3];
  }
#undef STAGE_QK
}

// K3: merge block partials (online-softmax weighted), write quarter 4 (NT).
__global__ __launch_bounds__(256) void k3_quarter4(const float* __restrict__ h,
    const float* __restrict__ partM, const float* __restrict__ partE,
    const float* __restrict__ partV, float* __restrict__ out) {
  int n = blockIdx.y, xc = blockIdx.x, t = threadIdx.x;
  __shared__ float sm[16], se[16];
  __shared__ float ht[DEN];
  if (t < 16) { sm[t] = partM[n * 16 + t]; se[t] = partE[n * 16 + t]; }
  __syncthreads();
  float M = sm[0];
#pragma unroll
  for (int c = 1; c < 16; ++c) M = fmaxf(M, sm[c]);
  float den = 0.f, s = 0.f;
#pragma unroll
  for (int c = 0; c < 16; ++c) {
    float fc = __expf(sm[c] - M);
    den += fc * se[c];
    s += fc * partV[((size_t)(n * 16 + c)) * 256 + t];
  }
  ht[t] = s / den;
  __syncthreads();
  int wave = t >> 6, c4 = t & 63;
  f32x4 htv = *(const f32x4*)(ht + c4 * 4);
#pragma unroll
  for (int i = 0; i < 8; ++i) {
    int row = xc * 32 + i * 4 + wave;
    f32x4 hv = *(const f32x4*)(h + (size_t)(n * JX + row) * DEN + c4 * 4);
    f32x4 hh = hv * htv;
    __builtin_nontemporal_store(hh,
        (f32x4*)(out + (size_t)(n * JX + row) * 1024 + 768 + c4 * 4));
  }
}

extern "C" void kernel_launch(void* const* d_in, const int* in_sizes, int n_in,
                              void* d_out, int out_size, void* d_ws, size_t ws_size,
                              hipStream_t stream) {
  const float* h = (const float*)d_in[0];
  const float* u = (const float*)d_in[1];
  float* out = (float*)d_out;
  char* ws = (char*)d_ws;

  size_t off = 0;
  unsigned short* u_hi = (unsigned short*)(ws + off); off += (size_t)NB * JQ * DEN * 2;
  unsigned short* u_lo = (unsigned short*)(ws + off); off += (size_t)NB * JQ * DEN * 2;
  _Float16* uT16 = (_Float16*)(ws + off); off += (size_t)NB * DEN * JQ * 2;
  float* partM = (float*)(ws + off); off += (size_t)NB * 16 * 4;
  float* partE = (float*)(ws + off); off += (size_t)NB * 16 * 4;
  float* partV = (float*)(ws + off); off += (size_t)NB * 16 * DEN * 4;

  hipLaunchKernelGGL(k0_prep_u, dim3(4, NB), dim3(256), 0, stream, u, u_hi, u_lo, uT16);
  hipLaunchKernelGGL(k1_attn, dim3(NB, JX / 128), dim3(256), 0, stream,
                     h, u_hi, u_lo, uT16, out, partM, partE, partV);
  hipLaunchKernelGGL(k3_quarter4, dim3(64, NB), dim3(256), 0, stream,
                     h, partM, partE, partV, out);
}

// Round 12
// 165.952 us; speedup vs baseline: 1.7201x; 1.3221x over previous
//
#include <hip/hip_runtime.h>
#include <stdint.h>

#define JX 2048
#define JQ 128
#define DEN 256
#define NB 64

typedef __attribute__((ext_vector_type(4))) float f32x4;
typedef __attribute__((ext_vector_type(8))) short short8;
typedef _Float16 f16x8 __attribute__((ext_vector_type(8)));

typedef __attribute__((address_space(1))) const unsigned int as1_uint;
typedef __attribute__((address_space(3))) unsigned int as3_uint;

__device__ __forceinline__ unsigned short f2bf(float f) {
  union { float f; unsigned int u; } v; v.f = f;
  unsigned int r = v.u + 0x7FFFu + ((v.u >> 16) & 1u);
  return (unsigned short)(r >> 16);
}
__device__ __forceinline__ float bf2f(unsigned short b) {
  union { float f; unsigned int u; } v; v.u = ((unsigned int)b) << 16;
  return v.f;
}
__device__ __forceinline__ void gload_lds16(const void* src, void* dst) {
  __builtin_amdgcn_global_load_lds((as1_uint*)src, (as3_uint*)dst, 16, 0, 0);
}
__device__ __forceinline__ unsigned pkh2(float a, float b) {
  union { _Float16 h[2]; unsigned u; } v;
  v.h[0] = (_Float16)a; v.h[1] = (_Float16)b; return v.u;
}

// hi/lo bf16 split of 8 f32 via v_cvt_pk_bf16_f32 (RNE, == f2bf bit pattern)
__device__ __forceinline__ void cvt_hilo8(const f32x4 x0, const f32x4 x1,
                                          short8* hi, short8* lo) {
  union { unsigned u[4]; short8 s; } H, L;
  float f[8];
#pragma unroll
  for (int j = 0; j < 4; ++j) { f[j] = x0[j]; f[4 + j] = x1[j]; }
#pragma unroll
  for (int k = 0; k < 4; ++k) {
    unsigned hk;
    asm("v_cvt_pk_bf16_f32 %0, %1, %2" : "=v"(hk) : "v"(f[2 * k]), "v"(f[2 * k + 1]));
    H.u[k] = hk;
    union { unsigned u; float fl; } h0, h1;
    h0.u = hk << 16;
    h1.u = hk & 0xffff0000u;
    float d0 = f[2 * k] - h0.fl;
    float d1 = f[2 * k + 1] - h1.fl;
    unsigned lk;
    asm("v_cvt_pk_bf16_f32 %0, %1, %2" : "=v"(lk) : "v"(d0), "v"(d1));
    L.u[k] = lk;
  }
  *hi = H.s;
  *lo = L.s;
}

// K0: u fp32 [n][128][256] -> u_hi,u_lo bf16 row-major + uT f16 [n][256][128]
__global__ __launch_bounds__(256) void k0_prep_u(const float* __restrict__ u,
    unsigned short* __restrict__ u_hi, unsigned short* __restrict__ u_lo,
    _Float16* __restrict__ uT16) {
  int n = blockIdx.y, dc = blockIdx.x, t = threadIdx.x;
  const float* un = u + (size_t)n * JQ * DEN;
  unsigned short* uhn = u_hi + (size_t)n * JQ * DEN;
  unsigned short* uln = u_lo + (size_t)n * JQ * DEN;
  __shared__ float lds[JQ * 65];
  for (int i = t; i < JQ * 64; i += 256) {
    int q = i >> 6, dl = i & 63;
    int idx = q * DEN + dc * 64 + dl;
    float f = un[idx];
    unsigned short hi = f2bf(f);
    uhn[idx] = hi;
    uln[idx] = f2bf(f - bf2f(hi));
    lds[q * 65 + dl] = f;
  }
  __syncthreads();
  _Float16* utn = uT16 + (size_t)n * DEN * JQ;
  for (int i = t; i < 64 * JQ; i += 256) {
    int dl = i >> 7, q = i & 127;
    utn[(size_t)(dc * 64 + dl) * JQ + q] = (_Float16)lds[q * 65 + dl];
  }
}

// K1: swapped-operand attention; transposed epilogue -> 256B full-line NT segments.
__global__ __launch_bounds__(256, 3) void k1_attn(
    const float* __restrict__ h, const unsigned short* __restrict__ u_hi,
    const unsigned short* __restrict__ u_lo, const _Float16* __restrict__ uT16,
    float* __restrict__ out, float* __restrict__ partM,
    float* __restrict__ partE, float* __restrict__ partV) {
  __shared__ __align__(16) unsigned char SA[32768];  // QK dbuf -> p-arena
  __shared__ __align__(16) unsigned char SB[16384];  // uT chunk / transpose scratch
  __shared__ float pvred[1024];                      // 16 g x 64 cols
  __shared__ float emvb[128];                        // exp(m_x - Mblk) per block row
  __shared__ float redM[4], redE[4];

  const int n = blockIdx.x, xb = blockIdx.y;
  const int tid = threadIdx.x;
  const int wave = tid >> 6, lane = tid & 63;
  const int l15 = lane & 15, lq = lane >> 4;
  const int rowbase = xb * 128 + wave * 32;

  const char* uhB = (const char*)(u_hi + (size_t)n * JQ * DEN);
  const char* ulB = (const char*)(u_lo + (size_t)n * JQ * DEN);
  const char* uTB = (const char*)(uT16 + (size_t)n * DEN * JQ);
  const float* hr0 = h + (size_t)(n * JX + rowbase + l15) * DEN;
  const float* hr1 = hr0 + (size_t)16 * DEN;

#define STAGE_QK(BUF, C)                                                     \
  {                                                                          \
    _Pragma("unroll")                                                        \
    for (int rr = 0; rr < 4; ++rr) {                                         \
      int L = rr * 4096 + tid * 16;                                          \
      int row = L >> 7;                                                      \
      int sb = ((L >> 4) & 7) ^ (row & 7);                                   \
      const char* s = (sb & 4) ? ulB : uhB;                                  \
      gload_lds16(s + (size_t)row * 512 + (C) * 64 + (sb & 3) * 16,          \
                  &SA[(BUF) * 16384 + L]);                                   \
    }                                                                        \
  }

  f32x4 acc[2][8];
#pragma unroll
  for (int t = 0; t < 2; ++t)
#pragma unroll
    for (int q = 0; q < 8; ++q) acc[t][q] = (f32x4)(0.f);

  STAGE_QK(0, 0);
  f32x4 hn[2][2];
  hn[0][0] = *(const f32x4*)(hr0 + lq * 8);
  hn[0][1] = *(const f32x4*)(hr0 + lq * 8 + 4);
  hn[1][0] = *(const f32x4*)(hr1 + lq * 8);
  hn[1][1] = *(const f32x4*)(hr1 + lq * 8 + 4);
  asm volatile("s_waitcnt vmcnt(4)" ::: "memory");
  __builtin_amdgcn_s_barrier();
  __builtin_amdgcn_sched_barrier(0);

#pragma unroll
  for (int c = 0; c < 8; ++c) {
    const int b = c & 1;
    if (c < 7) STAGE_QK(b ^ 1, c + 1);
    f32x4 hc[2][2];
#pragma unroll
    for (int t = 0; t < 2; ++t) { hc[t][0] = hn[t][0]; hc[t][1] = hn[t][1]; }
    if (c < 7) {
      hn[0][0] = *(const f32x4*)(hr0 + (c + 1) * 32 + lq * 8);
      hn[0][1] = *(const f32x4*)(hr0 + (c + 1) * 32 + lq * 8 + 4);
      hn[1][0] = *(const f32x4*)(hr1 + (c + 1) * 32 + lq * 8);
      hn[1][1] = *(const f32x4*)(hr1 + (c + 1) * 32 + lq * 8 + 4);
    }
    short8 bhi[2], blo[2];
#pragma unroll
    for (int t = 0; t < 2; ++t) cvt_hilo8(hc[t][0], hc[t][1], &bhi[t], &blo[t]);
    __builtin_amdgcn_s_setprio(1);
#pragma unroll
    for (int qt = 0; qt < 8; ++qt) {
      int row = qt * 16 + l15;
      const short8 uhf = *(const short8*)(&SA[b * 16384 + row * 128 + ((lq ^ (row & 7)) << 4)]);
      const short8 ulf = *(const short8*)(&SA[b * 16384 + row * 128 + (((4 | lq) ^ (row & 7)) << 4)]);
      acc[0][qt] = __builtin_amdgcn_mfma_f32_16x16x32_bf16(ulf, bhi[0], acc[0][qt], 0, 0, 0);
      acc[0][qt] = __builtin_amdgcn_mfma_f32_16x16x32_bf16(uhf, blo[0], acc[0][qt], 0, 0, 0);
      acc[0][qt] = __builtin_amdgcn_mfma_f32_16x16x32_bf16(uhf, bhi[0], acc[0][qt], 0, 0, 0);
      acc[1][qt] = __builtin_amdgcn_mfma_f32_16x16x32_bf16(ulf, bhi[1], acc[1][qt], 0, 0, 0);
      acc[1][qt] = __builtin_amdgcn_mfma_f32_16x16x32_bf16(uhf, blo[1], acc[1][qt], 0, 0, 0);
      acc[1][qt] = __builtin_amdgcn_mfma_f32_16x16x32_bf16(uhf, bhi[1], acc[1][qt], 0, 0, 0);
    }
    __builtin_amdgcn_s_setprio(0);
    if (c < 7) {
      asm volatile("s_waitcnt vmcnt(4)" ::: "memory");
      __builtin_amdgcn_s_barrier();
      __builtin_amdgcn_sched_barrier(0);
    }
  }

  // stage uT chunk 0 (drained at the redM __syncthreads below)
  {
#pragma unroll
    for (int rr = 0; rr < 4; ++rr) {
      int L = rr * 4096 + tid * 16;
      int row = L >> 8;
      int cb = ((L >> 4) & 15) ^ (row & 7);
      gload_lds16(uTB + (size_t)(row)*256 + cb * 16, &SB[L]);
    }
  }

  // softmax over q (x = l15 lane-local, replicated across lq)
  float mvt[2], rinv[2];
#pragma unroll
  for (int t = 0; t < 2; ++t) {
    float mv = acc[t][0][0];
#pragma unroll
    for (int qt = 0; qt < 8; ++qt)
#pragma unroll
      for (int r = 0; r < 4; ++r) mv = fmaxf(mv, acc[t][qt][r]);
    mv = fmaxf(mv, __shfl_xor(mv, 16));
    mv = fmaxf(mv, __shfl_xor(mv, 32));
    float s = 0.f;
#pragma unroll
    for (int qt = 0; qt < 8; ++qt)
#pragma unroll
      for (int r = 0; r < 4; ++r) {
        float p = __expf(acc[t][qt][r] - mv);
        acc[t][qt][r] = p;
        s += p;
      }
    s += __shfl_xor(s, 16);
    s += __shfl_xor(s, 32);
    mvt[t] = mv;
    rinv[t] = 1.f / s;
  }

  float wmax = fmaxf(mvt[0], mvt[1]);
  wmax = fmaxf(wmax, __shfl_xor(wmax, 1));
  wmax = fmaxf(wmax, __shfl_xor(wmax, 2));
  wmax = fmaxf(wmax, __shfl_xor(wmax, 4));
  wmax = fmaxf(wmax, __shfl_xor(wmax, 8));
  if (lane == 0) redM[wave] = wmax;
  __syncthreads();  // redM visible; SB chunk 0 drained; SA safe to reuse
  const float Mblk = fmaxf(fmaxf(redM[0], redM[1]), fmaxf(redM[2], redM[3]));
  const float w0 = __expf(mvt[0] - Mblk);
  const float w1 = __expf(mvt[1] - Mblk);
  if (lq == 0) {
    emvb[wave * 32 + l15] = w0;
    emvb[wave * 32 + 16 + l15] = w1;
  }
  float es = w0 + w1;
  es += __shfl_xor(es, 1);
  es += __shfl_xor(es, 2);
  es += __shfl_xor(es, 4);
  es += __shfl_xor(es, 8);
  if (lane == 0) redE[wave] = es;

  // pack p (unnormalized, joint-t) into per-wave arena in SA
  char* pw = (char*)SA + wave * 8192;
  const int swz = (l15 & 7) << 4;
#pragma unroll
  for (int t = 0; t < 2; ++t)
#pragma unroll
    for (int qt = 0; qt < 8; ++qt) {
      union { unsigned u2[2]; uint2 u; } pk;
      pk.u2[0] = pkh2(acc[t][qt][0], acc[t][qt][1]);
      pk.u2[1] = pkh2(acc[t][qt][2], acc[t][qt][3]);
      *(uint2*)(pw + (t * 16 + l15) * 256 + ((32 * qt + 8 * lq) ^ swz)) = pk.u;
    }

  // prefetch uT regs for chunk 1
  f32x4 sbreg[4];
#pragma unroll
  for (int rr = 0; rr < 4; ++rr) {
    int L = rr * 4096 + tid * 16;
    int row = L >> 8;
    int cb = ((L >> 4) & 15) ^ (row & 7);
    sbreg[rr] = *(const f32x4*)(uTB + (size_t)(64 + row) * 256 + cb * 16);
  }

  char* myscr = (char*)SB + wave * 4096;  // per-wave transpose scratch (4KB)

  // PV + transposed epilogue: 4 chunks of 64 d-cols
#pragma unroll
  for (int c = 0; c < 4; ++c) {
    f32x4 vacc[2][4];
#pragma unroll
    for (int t = 0; t < 2; ++t)
#pragma unroll
      for (int dt = 0; dt < 4; ++dt) vacc[t][dt] = (f32x4)(0.f);
    __builtin_amdgcn_s_setprio(1);
#pragma unroll
    for (int ks = 0; ks < 4; ++ks) {
      f16x8 pf[2];
#pragma unroll
      for (int t = 0; t < 2; ++t)
        pf[t] = *(const f16x8*)(pw + (t * 16 + l15) * 256 + ((64 * ks + 16 * lq) ^ swz));
#pragma unroll
      for (int dt = 0; dt < 4; ++dt) {
        int row = dt * 16 + l15;
        const f16x8 Af = *(const f16x8*)(&SB[row * 256 + (((4 * ks + lq) ^ (row & 7)) << 4)]);
        vacc[0][dt] = __builtin_amdgcn_mfma_f32_16x16x32_f16(Af, pf[0], vacc[0][dt], 0, 0, 0);
        vacc[1][dt] = __builtin_amdgcn_mfma_f32_16x16x32_f16(Af, pf[1], vacc[1][dt], 0, 0, 0);
      }
    }
    __builtin_amdgcn_s_setprio(0);

    // barrier1: all waves done reading SB chunk c -> SB becomes scratch
    asm volatile("s_waitcnt lgkmcnt(0)" ::: "memory");
    __builtin_amdgcn_s_barrier();
    __builtin_amdgcn_sched_barrier(0);

    f32x4 pacc = (f32x4)(0.f);
#pragma unroll
    for (int t = 0; t < 2; ++t) {
      // wave-private transpose: write 16 rows x 64 cols (normalized), XOR-swz
#pragma unroll
      for (int dt = 0; dt < 4; ++dt) {
        f32x4 v = vacc[t][dt] * rinv[t];
        *(f32x4*)(myscr + l15 * 256 + (((dt * 4 + lq) ^ l15) << 4)) = v;
      }
      asm volatile("s_waitcnt lgkmcnt(0)" ::: "memory");
      __builtin_amdgcn_sched_barrier(0);
      // row-major readback + 256B full-line NT stores (4 rows/instr x 256B)
      f32x4 utv[4], hvv[4];
#pragma unroll
      for (int i = 0; i < 4; ++i) {
        int rl = i * 4 + lq;
        utv[i] = *(const f32x4*)(myscr + rl * 256 + ((l15 ^ rl) << 4));
        hvv[i] = *(const f32x4*)(h + (size_t)(n * JX + rowbase + t * 16 + rl) * DEN +
                                 c * 64 + l15 * 4);
      }
#pragma unroll
      for (int i = 0; i < 4; ++i) {
        int rl = i * 4 + lq;
        float* op = out + (size_t)(n * JX + rowbase + t * 16 + rl) * 1024 + c * 64 + l15 * 4;
        __builtin_nontemporal_store(hvv[i], (f32x4*)op);
        __builtin_nontemporal_store(utv[i], (f32x4*)(op + 256));
        __builtin_nontemporal_store(hvv[i] * utv[i], (f32x4*)(op + 512));
        pacc += hvv[i] * emvb[wave * 32 + t * 16 + rl];
      }
      asm volatile("s_waitcnt lgkmcnt(0)" ::: "memory");
      __builtin_amdgcn_sched_barrier(0);
    }

    // flush h_tilde partials: pvred[g][col] then wave0 sums
    {
      int g = wave * 4 + lq;
      *(f32x4*)(&pvred[g * 64 + l15 * 4]) = pacc;
    }
    // barrier2a: pvred visible + all waves done with scratch
    asm volatile("s_waitcnt lgkmcnt(0)" ::: "memory");
    __builtin_amdgcn_s_barrier();
    __builtin_amdgcn_sched_barrier(0);
    if (tid < 64) {
      float s = 0.f;
#pragma unroll
      for (int g2 = 0; g2 < 16; ++g2) s += pvred[g2 * 64 + tid];
      partV[((size_t)(n * 16 + xb)) * 256 + c * 64 + tid] = s;
    }
    if (c < 3) {
      // refill SB with chunk c+1 (pre-loaded), then prefetch chunk c+2
#pragma unroll
      for (int rr = 0; rr < 4; ++rr)
        *(f32x4*)(&SB[rr * 4096 + tid * 16]) = sbreg[rr];
      if (c < 2) {
#pragma unroll
        for (int rr = 0; rr < 4; ++rr) {
          int L = rr * 4096 + tid * 16;
          int row = L >> 8;
          int cb = ((L >> 4) & 15) ^ (row & 7);
          sbreg[rr] = *(const f32x4*)(uTB + (size_t)((c + 2) * 64 + row) * 256 + cb * 16);
        }
      }
      // barrier2b: refill visible before next chunk's MFMAs
      asm volatile("s_waitcnt lgkmcnt(0)" ::: "memory");
      __builtin_amdgcn_s_barrier();
      __builtin_amdgcn_sched_barrier(0);
    }
  }

  if (tid == 0) {
    partM[n * 16 + xb] = Mblk;
    partE[n * 16 + xb] = redE[0] + redE[1] + redE[2] + redE[3];
  }
#undef STAGE_QK
}

// K3: merge block partials (online-softmax weighted), write quarter 4 (NT).
__global__ __launch_bounds__(256) void k3_quarter4(const float* __restrict__ h,
    const float* __restrict__ partM, const float* __restrict__ partE,
    const float* __restrict__ partV, float* __restrict__ out) {
  int n = blockIdx.y, xc = blockIdx.x, t = threadIdx.x;
  __shared__ float sm[16], se[16];
  __shared__ float ht[DEN];
  if (t < 16) { sm[t] = partM[n * 16 + t]; se[t] = partE[n * 16 + t]; }
  __syncthreads();
  float M = sm[0];
#pragma unroll
  for (int c = 1; c < 16; ++c) M = fmaxf(M, sm[c]);
  float den = 0.f, s = 0.f;
#pragma unroll
  for (int c = 0; c < 16; ++c) {
    float fc = __expf(sm[c] - M);
    den += fc * se[c];
    s += fc * partV[((size_t)(n * 16 + c)) * 256 + t];
  }
  ht[t] = s / den;
  __syncthreads();
  int wave = t >> 6, c4 = t & 63;
  f32x4 htv = *(const f32x4*)(ht + c4 * 4);
#pragma unroll
  for (int i = 0; i < 8; ++i) {
    int row = xc * 32 + i * 4 + wave;
    f32x4 hv = *(const f32x4*)(h + (size_t)(n * JX + row) * DEN + c4 * 4);
    f32x4 hh = hv * htv;
    __builtin_nontemporal_store(hh,
        (f32x4*)(out + (size_t)(n * JX + row) * 1024 + 768 + c4 * 4));
  }
}

extern "C" void kernel_launch(void* const* d_in, const int* in_sizes, int n_in,
                              void* d_out, int out_size, void* d_ws, size_t ws_size,
                              hipStream_t stream) {
  const float* h = (const float*)d_in[0];
  const float* u = (const float*)d_in[1];
  float* out = (float*)d_out;
  char* ws = (char*)d_ws;

  size_t off = 0;
  unsigned short* u_hi = (unsigned short*)(ws + off); off += (size_t)NB * JQ * DEN * 2;
  unsigned short* u_lo = (unsigned short*)(ws + off); off += (size_t)NB * JQ * DEN * 2;
  _Float16* uT16 = (_Float16*)(ws + off); off += (size_t)NB * DEN * JQ * 2;
  float* partM = (float*)(ws + off); off += (size_t)NB * 16 * 4;
  float* partE = (float*)(ws + off); off += (size_t)NB * 16 * 4;
  float* partV = (float*)(ws + off); off += (size_t)NB * 16 * DEN * 4;

  hipLaunchKernelGGL(k0_prep_u, dim3(4, NB), dim3(256), 0, stream, u, u_hi, u_lo, uT16);
  hipLaunchKernelGGL(k1_attn, dim3(NB, JX / 128), dim3(256), 0, stream,
                     h, u_hi, u_lo, uT16, out, partM, partE, partV);
  hipLaunchKernelGGL(k3_quarter4, dim3(64, NB), dim3(256), 0, stream,
                     h, partM, partE, partV, out);
}

// Round 13
// 165.867 us; speedup vs baseline: 1.7210x; 1.0005x over previous
//
#include <hip/hip_runtime.h>
#include <stdint.h>

#define JX 2048
#define JQ 128
#define DEN 256
#define NB 64

typedef __attribute__((ext_vector_type(4))) float f32x4;
typedef __attribute__((ext_vector_type(8))) short short8;
typedef _Float16 f16x8 __attribute__((ext_vector_type(8)));

typedef __attribute__((address_space(1))) const unsigned int as1_uint;
typedef __attribute__((address_space(3))) unsigned int as3_uint;

__device__ __forceinline__ unsigned short f2bf(float f) {
  union { float f; unsigned int u; } v; v.f = f;
  unsigned int r = v.u + 0x7FFFu + ((v.u >> 16) & 1u);
  return (unsigned short)(r >> 16);
}
__device__ __forceinline__ float bf2f(unsigned short b) {
  union { float f; unsigned int u; } v; v.u = ((unsigned int)b) << 16;
  return v.f;
}
__device__ __forceinline__ void gload_lds16(const void* src, void* dst) {
  __builtin_amdgcn_global_load_lds((as1_uint*)src, (as3_uint*)dst, 16, 0, 0);
}
__device__ __forceinline__ unsigned pkh2(float a, float b) {
  union { _Float16 h[2]; unsigned u; } v;
  v.h[0] = (_Float16)a; v.h[1] = (_Float16)b; return v.u;
}

// hi/lo bf16 split of 8 f32 via v_cvt_pk_bf16_f32 (RNE, == f2bf bit pattern)
__device__ __forceinline__ void cvt_hilo8(const f32x4 x0, const f32x4 x1,
                                          short8* hi, short8* lo) {
  union { unsigned u[4]; short8 s; } H, L;
  float f[8];
#pragma unroll
  for (int j = 0; j < 4; ++j) { f[j] = x0[j]; f[4 + j] = x1[j]; }
#pragma unroll
  for (int k = 0; k < 4; ++k) {
    unsigned hk;
    asm("v_cvt_pk_bf16_f32 %0, %1, %2" : "=v"(hk) : "v"(f[2 * k]), "v"(f[2 * k + 1]));
    H.u[k] = hk;
    union { unsigned u; float fl; } h0, h1;
    h0.u = hk << 16;
    h1.u = hk & 0xffff0000u;
    float d0 = f[2 * k] - h0.fl;
    float d1 = f[2 * k + 1] - h1.fl;
    unsigned lk;
    asm("v_cvt_pk_bf16_f32 %0, %1, %2" : "=v"(lk) : "v"(d0), "v"(d1));
    L.u[k] = lk;
  }
  *hi = H.s;
  *lo = L.s;
}

// K0: u fp32 [n][128][256] -> u_hi,u_lo bf16 row-major + uT f16 [n][256][128]
__global__ __launch_bounds__(256) void k0_prep_u(const float* __restrict__ u,
    unsigned short* __restrict__ u_hi, unsigned short* __restrict__ u_lo,
    _Float16* __restrict__ uT16) {
  int n = blockIdx.y, dc = blockIdx.x, t = threadIdx.x;
  const float* un = u + (size_t)n * JQ * DEN;
  unsigned short* uhn = u_hi + (size_t)n * JQ * DEN;
  unsigned short* uln = u_lo + (size_t)n * JQ * DEN;
  __shared__ float lds[JQ * 65];
  for (int i = t; i < JQ * 64; i += 256) {
    int q = i >> 6, dl = i & 63;
    int idx = q * DEN + dc * 64 + dl;
    float f = un[idx];
    unsigned short hi = f2bf(f);
    uhn[idx] = hi;
    uln[idx] = f2bf(f - bf2f(hi));
    lds[q * 65 + dl] = f;
  }
  __syncthreads();
  _Float16* utn = uT16 + (size_t)n * DEN * JQ;
  for (int i = t; i < 64 * JQ; i += 256) {
    int dl = i >> 7, q = i & 127;
    utn[(size_t)(dc * 64 + dl) * JQ + q] = (_Float16)lds[q * 65 + dl];
  }
}

// K1: swapped-operand attention; transposed full-line-NT epilogue; thin barriers.
__global__ __launch_bounds__(256, 3) void k1_attn(
    const float* __restrict__ h, const unsigned short* __restrict__ u_hi,
    const unsigned short* __restrict__ u_lo, const _Float16* __restrict__ uT16,
    float* __restrict__ out, float* __restrict__ partM,
    float* __restrict__ partE, float* __restrict__ partV) {
  __shared__ __align__(16) unsigned char SA[32768];  // QK dbuf -> p-arena
  __shared__ __align__(16) unsigned char SB[16384];  // uT chunk / transpose scratch
  __shared__ float pvred[4][4][64];                  // [wave][chunk][col] h~ partials
  __shared__ float emvb[128];                        // exp(m_x - Mblk) per block row
  __shared__ float redM[4], redE[4];

  const int n = blockIdx.x, xb = blockIdx.y;
  const int tid = threadIdx.x;
  const int wave = tid >> 6, lane = tid & 63;
  const int l15 = lane & 15, lq = lane >> 4;
  const int rowbase = xb * 128 + wave * 32;

  const char* uhB = (const char*)(u_hi + (size_t)n * JQ * DEN);
  const char* ulB = (const char*)(u_lo + (size_t)n * JQ * DEN);
  const char* uTB = (const char*)(uT16 + (size_t)n * DEN * JQ);
  const float* hr0 = h + (size_t)(n * JX + rowbase + l15) * DEN;
  const float* hr1 = hr0 + (size_t)16 * DEN;

#define STAGE_QK(BUF, C)                                                     \
  {                                                                          \
    _Pragma("unroll")                                                        \
    for (int rr = 0; rr < 4; ++rr) {                                         \
      int L = rr * 4096 + tid * 16;                                          \
      int row = L >> 7;                                                      \
      int sb = ((L >> 4) & 7) ^ (row & 7);                                   \
      const char* s = (sb & 4) ? ulB : uhB;                                  \
      gload_lds16(s + (size_t)row * 512 + (C) * 64 + (sb & 3) * 16,          \
                  &SA[(BUF) * 16384 + L]);                                   \
    }                                                                        \
  }

  f32x4 acc[2][8];
#pragma unroll
  for (int t = 0; t < 2; ++t)
#pragma unroll
    for (int q = 0; q < 8; ++q) acc[t][q] = (f32x4)(0.f);

  STAGE_QK(0, 0);
  f32x4 hn[2][2];
  hn[0][0] = *(const f32x4*)(hr0 + lq * 8);
  hn[0][1] = *(const f32x4*)(hr0 + lq * 8 + 4);
  hn[1][0] = *(const f32x4*)(hr1 + lq * 8);
  hn[1][1] = *(const f32x4*)(hr1 + lq * 8 + 4);
  asm volatile("s_waitcnt vmcnt(4)" ::: "memory");
  __builtin_amdgcn_s_barrier();
  __builtin_amdgcn_sched_barrier(0);

#pragma unroll
  for (int c = 0; c < 8; ++c) {
    const int b = c & 1;
    if (c < 7) STAGE_QK(b ^ 1, c + 1);
    f32x4 hc[2][2];
#pragma unroll
    for (int t = 0; t < 2; ++t) { hc[t][0] = hn[t][0]; hc[t][1] = hn[t][1]; }
    if (c < 7) {
      hn[0][0] = *(const f32x4*)(hr0 + (c + 1) * 32 + lq * 8);
      hn[0][1] = *(const f32x4*)(hr0 + (c + 1) * 32 + lq * 8 + 4);
      hn[1][0] = *(const f32x4*)(hr1 + (c + 1) * 32 + lq * 8);
      hn[1][1] = *(const f32x4*)(hr1 + (c + 1) * 32 + lq * 8 + 4);
    }
    short8 bhi[2], blo[2];
#pragma unroll
    for (int t = 0; t < 2; ++t) cvt_hilo8(hc[t][0], hc[t][1], &bhi[t], &blo[t]);
    __builtin_amdgcn_s_setprio(1);
#pragma unroll
    for (int qt = 0; qt < 8; ++qt) {
      int row = qt * 16 + l15;
      const short8 uhf = *(const short8*)(&SA[b * 16384 + row * 128 + ((lq ^ (row & 7)) << 4)]);
      const short8 ulf = *(const short8*)(&SA[b * 16384 + row * 128 + (((4 | lq) ^ (row & 7)) << 4)]);
      acc[0][qt] = __builtin_amdgcn_mfma_f32_16x16x32_bf16(ulf, bhi[0], acc[0][qt], 0, 0, 0);
      acc[0][qt] = __builtin_amdgcn_mfma_f32_16x16x32_bf16(uhf, blo[0], acc[0][qt], 0, 0, 0);
      acc[0][qt] = __builtin_amdgcn_mfma_f32_16x16x32_bf16(uhf, bhi[0], acc[0][qt], 0, 0, 0);
      acc[1][qt] = __builtin_amdgcn_mfma_f32_16x16x32_bf16(ulf, bhi[1], acc[1][qt], 0, 0, 0);
      acc[1][qt] = __builtin_amdgcn_mfma_f32_16x16x32_bf16(uhf, blo[1], acc[1][qt], 0, 0, 0);
      acc[1][qt] = __builtin_amdgcn_mfma_f32_16x16x32_bf16(uhf, bhi[1], acc[1][qt], 0, 0, 0);
    }
    __builtin_amdgcn_s_setprio(0);
    if (c < 7) {
      asm volatile("s_waitcnt vmcnt(4)" ::: "memory");
      __builtin_amdgcn_s_barrier();
      __builtin_amdgcn_sched_barrier(0);
    }
  }

  // stage uT chunk 0 (drained at the redM __syncthreads below)
  {
#pragma unroll
    for (int rr = 0; rr < 4; ++rr) {
      int L = rr * 4096 + tid * 16;
      int row = L >> 8;
      int cb = ((L >> 4) & 15) ^ (row & 7);
      gload_lds16(uTB + (size_t)(row)*256 + cb * 16, &SB[L]);
    }
  }

  // softmax over q (x = l15 lane-local, replicated across lq)
  float mvt[2], rinv[2];
#pragma unroll
  for (int t = 0; t < 2; ++t) {
    float mv = acc[t][0][0];
#pragma unroll
    for (int qt = 0; qt < 8; ++qt)
#pragma unroll
      for (int r = 0; r < 4; ++r) mv = fmaxf(mv, acc[t][qt][r]);
    mv = fmaxf(mv, __shfl_xor(mv, 16));
    mv = fmaxf(mv, __shfl_xor(mv, 32));
    float s = 0.f;
#pragma unroll
    for (int qt = 0; qt < 8; ++qt)
#pragma unroll
      for (int r = 0; r < 4; ++r) {
        float p = __expf(acc[t][qt][r] - mv);
        acc[t][qt][r] = p;
        s += p;
      }
    s += __shfl_xor(s, 16);
    s += __shfl_xor(s, 32);
    mvt[t] = mv;
    rinv[t] = 1.f / s;
  }

  float wmax = fmaxf(mvt[0], mvt[1]);
  wmax = fmaxf(wmax, __shfl_xor(wmax, 1));
  wmax = fmaxf(wmax, __shfl_xor(wmax, 2));
  wmax = fmaxf(wmax, __shfl_xor(wmax, 4));
  wmax = fmaxf(wmax, __shfl_xor(wmax, 8));
  if (lane == 0) redM[wave] = wmax;
  __syncthreads();  // redM visible; SB chunk 0 drained; SA safe to reuse
  const float Mblk = fmaxf(fmaxf(redM[0], redM[1]), fmaxf(redM[2], redM[3]));
  const float w0 = __expf(mvt[0] - Mblk);
  const float w1 = __expf(mvt[1] - Mblk);
  if (lq == 0) {
    emvb[wave * 32 + l15] = w0;
    emvb[wave * 32 + 16 + l15] = w1;
  }
  float es = w0 + w1;
  es += __shfl_xor(es, 1);
  es += __shfl_xor(es, 2);
  es += __shfl_xor(es, 4);
  es += __shfl_xor(es, 8);
  if (lane == 0) redE[wave] = es;

  // pack p (unnormalized, joint-t) into per-wave arena in SA
  char* pw = (char*)SA + wave * 8192;
  const int swz = (l15 & 7) << 4;
#pragma unroll
  for (int t = 0; t < 2; ++t)
#pragma unroll
    for (int qt = 0; qt < 8; ++qt) {
      union { unsigned u2[2]; uint2 u; } pk;
      pk.u2[0] = pkh2(acc[t][qt][0], acc[t][qt][1]);
      pk.u2[1] = pkh2(acc[t][qt][2], acc[t][qt][3]);
      *(uint2*)(pw + (t * 16 + l15) * 256 + ((32 * qt + 8 * lq) ^ swz)) = pk.u;
    }

  // prefetch uT regs for chunk 1 (wave-local slice mapping)
  f32x4 sbreg[4];
#pragma unroll
  for (int rr = 0; rr < 4; ++rr) {
    int L = wave * 4096 + rr * 1024 + lane * 16;
    int row = L >> 8;
    int cb = ((L >> 4) & 15) ^ (row & 7);
    sbreg[rr] = *(const f32x4*)(uTB + (size_t)(64 + row) * 256 + cb * 16);
  }

  char* myscr = (char*)SB + wave * 4096;  // per-wave transpose scratch (4KB)

  // PV + transposed epilogue: 4 chunks of 64 d-cols; 2 barriers/chunk
#pragma unroll
  for (int c = 0; c < 4; ++c) {
    f32x4 vacc[2][4];
#pragma unroll
    for (int t = 0; t < 2; ++t)
#pragma unroll
      for (int dt = 0; dt < 4; ++dt) vacc[t][dt] = (f32x4)(0.f);
    __builtin_amdgcn_s_setprio(1);
#pragma unroll
    for (int ks = 0; ks < 4; ++ks) {
      f16x8 pf[2];
#pragma unroll
      for (int t = 0; t < 2; ++t)
        pf[t] = *(const f16x8*)(pw + (t * 16 + l15) * 256 + ((64 * ks + 16 * lq) ^ swz));
#pragma unroll
      for (int dt = 0; dt < 4; ++dt) {
        int row = dt * 16 + l15;
        const f16x8 Af = *(const f16x8*)(&SB[row * 256 + (((4 * ks + lq) ^ (row & 7)) << 4)]);
        vacc[0][dt] = __builtin_amdgcn_mfma_f32_16x16x32_f16(Af, pf[0], vacc[0][dt], 0, 0, 0);
        vacc[1][dt] = __builtin_amdgcn_mfma_f32_16x16x32_f16(Af, pf[1], vacc[1][dt], 0, 0, 0);
      }
    }
    __builtin_amdgcn_s_setprio(0);

    // barrier1: all waves done reading SB chunk c -> slices become scratch
    asm volatile("s_waitcnt lgkmcnt(0)" ::: "memory");
    __builtin_amdgcn_s_barrier();
    __builtin_amdgcn_sched_barrier(0);

    f32x4 pacc = (f32x4)(0.f);
#pragma unroll
    for (int t = 0; t < 2; ++t) {
      // wave-private transpose: write 16 rows x 64 cols (normalized), XOR-swz
#pragma unroll
      for (int dt = 0; dt < 4; ++dt) {
        f32x4 v = vacc[t][dt] * rinv[t];
        *(f32x4*)(myscr + l15 * 256 + (((dt * 4 + lq) ^ l15) << 4)) = v;
      }
      asm volatile("s_waitcnt lgkmcnt(0)" ::: "memory");
      __builtin_amdgcn_sched_barrier(0);
      // row-major readback + 256B full-line NT stores (4 rows/instr x 256B)
      f32x4 utv[4], hvv[4];
#pragma unroll
      for (int i = 0; i < 4; ++i) {
        int rl = i * 4 + lq;
        utv[i] = *(const f32x4*)(myscr + rl * 256 + ((l15 ^ rl) << 4));
        hvv[i] = *(const f32x4*)(h + (size_t)(n * JX + rowbase + t * 16 + rl) * DEN +
                                 c * 64 + l15 * 4);
      }
#pragma unroll
      for (int i = 0; i < 4; ++i) {
        int rl = i * 4 + lq;
        float* op = out + (size_t)(n * JX + rowbase + t * 16 + rl) * 1024 + c * 64 + l15 * 4;
        __builtin_nontemporal_store(hvv[i], (f32x4*)op);
        __builtin_nontemporal_store(utv[i], (f32x4*)(op + 256));
        __builtin_nontemporal_store(hvv[i] * utv[i], (f32x4*)(op + 512));
        pacc += hvv[i] * emvb[wave * 32 + t * 16 + rl];
      }
      asm volatile("s_waitcnt lgkmcnt(0)" ::: "memory");
      __builtin_amdgcn_sched_barrier(0);
    }

    // lq-reduce pacc in-wave, store to wave-private pvred slot (no barrier)
#pragma unroll
    for (int j = 0; j < 4; ++j) {
      pacc[j] += __shfl_xor(pacc[j], 16);
      pacc[j] += __shfl_xor(pacc[j], 32);
    }
    if (lq == 0) *(f32x4*)(&pvred[wave][c][l15 * 4]) = pacc;

    if (c < 3) {
      // refill OWN slice of SB with pre-loaded chunk c+1, prefetch c+2
#pragma unroll
      for (int rr = 0; rr < 4; ++rr)
        *(f32x4*)(&SB[wave * 4096 + rr * 1024 + lane * 16]) = sbreg[rr];
      if (c < 2) {
#pragma unroll
        for (int rr = 0; rr < 4; ++rr) {
          int L = wave * 4096 + rr * 1024 + lane * 16;
          int row = L >> 8;
          int cb = ((L >> 4) & 15) ^ (row & 7);
          sbreg[rr] = *(const f32x4*)(uTB + (size_t)((c + 2) * 64 + row) * 256 + cb * 16);
        }
      }
      // barrier2: all slices refilled before next chunk's MFMAs
      asm volatile("s_waitcnt lgkmcnt(0)" ::: "memory");
      __builtin_amdgcn_s_barrier();
      __builtin_amdgcn_sched_barrier(0);
    }
  }

  __syncthreads();  // pvred + redE visible
  {
    int cc = tid >> 6, col = tid & 63;
    float s = pvred[0][cc][col] + pvred[1][cc][col] +
              pvred[2][cc][col] + pvred[3][cc][col];
    partV[((size_t)(n * 16 + xb)) * 256 + tid] = s;
  }
  if (tid == 0) {
    partM[n * 16 + xb] = Mblk;
    partE[n * 16 + xb] = redE[0] + redE[1] + redE[2] + redE[3];
  }
#undef STAGE_QK
}

// K3: merge block partials (online-softmax weighted), write quarter 4 (NT).
__global__ __launch_bounds__(256) void k3_quarter4(const float* __restrict__ h,
    const float* __restrict__ partM, const float* __restrict__ partE,
    const float* __restrict__ partV, float* __restrict__ out) {
  int n = blockIdx.y, xc = blockIdx.x, t = threadIdx.x;
  __shared__ float sm[16], se[16];
  __shared__ float ht[DEN];
  if (t < 16) { sm[t] = partM[n * 16 + t]; se[t] = partE[n * 16 + t]; }
  __syncthreads();
  float M = sm[0];
#pragma unroll
  for (int c = 1; c < 16; ++c) M = fmaxf(M, sm[c]);
  float den = 0.f, s = 0.f;
#pragma unroll
  for (int c = 0; c < 16; ++c) {
    float fc = __expf(sm[c] - M);
    den += fc * se[c];
    s += fc * partV[((size_t)(n * 16 + c)) * 256 + t];
  }
  ht[t] = s / den;
  __syncthreads();
  int wave = t >> 6, c4 = t & 63;
  f32x4 htv = *(const f32x4*)(ht + c4 * 4);
#pragma unroll
  for (int i = 0; i < 8; ++i) {
    int row = xc * 32 + i * 4 + wave;
    f32x4 hv = *(const f32x4*)(h + (size_t)(n * JX + row) * DEN + c4 * 4);
    f32x4 hh = hv * htv;
    __builtin_nontemporal_store(hh,
        (f32x4*)(out + (size_t)(n * JX + row) * 1024 + 768 + c4 * 4));
  }
}

extern "C" void kernel_launch(void* const* d_in, const int* in_sizes, int n_in,
                              void* d_out, int out_size, void* d_ws, size_t ws_size,
                              hipStream_t stream) {
  const float* h = (const float*)d_in[0];
  const float* u = (const float*)d_in[1];
  float* out = (float*)d_out;
  char* ws = (char*)d_ws;

  size_t off = 0;
  unsigned short* u_hi = (unsigned short*)(ws + off); off += (size_t)NB * JQ * DEN * 2;
  unsigned short* u_lo = (unsigned short*)(ws + off); off += (size_t)NB * JQ * DEN * 2;
  _Float16* uT16 = (_Float16*)(ws + off); off += (size_t)NB * DEN * JQ * 2;
  float* partM = (float*)(ws + off); off += (size_t)NB * 16 * 4;
  float* partE = (float*)(ws + off); off += (size_t)NB * 16 * 4;
  float* partV = (float*)(ws + off); off += (size_t)NB * 16 * DEN * 4;

  hipLaunchKernelGGL(k0_prep_u, dim3(4, NB), dim3(256), 0, stream, u, u_hi, u_lo, uT16);
  hipLaunchKernelGGL(k1_attn, dim3(NB, JX / 128), dim3(256), 0, stream,
                     h, u_hi, u_lo, uT16, out, partM, partE, partV);
  hipLaunchKernelGGL(k3_quarter4, dim3(64, NB), dim3(256), 0, stream,
                     h, partM, partE, partV, out);
}

// Round 14
// 165.579 us; speedup vs baseline: 1.7239x; 1.0017x over previous
//
#include <hip/hip_runtime.h>
#include <stdint.h>

#define JX 2048
#define JQ 128
#define DEN 256
#define NB 64

typedef __attribute__((ext_vector_type(4))) float f32x4;
typedef __attribute__((ext_vector_type(8))) short short8;
typedef _Float16 f16x8 __attribute__((ext_vector_type(8)));

typedef __attribute__((address_space(1))) const unsigned int as1_uint;
typedef __attribute__((address_space(3))) unsigned int as3_uint;

__device__ __forceinline__ unsigned short f2bf(float f) {
  union { float f; unsigned int u; } v; v.f = f;
  unsigned int r = v.u + 0x7FFFu + ((v.u >> 16) & 1u);
  return (unsigned short)(r >> 16);
}
__device__ __forceinline__ float bf2f(unsigned short b) {
  union { float f; unsigned int u; } v; v.u = ((unsigned int)b) << 16;
  return v.f;
}
__device__ __forceinline__ void gload_lds16(const void* src, void* dst) {
  __builtin_amdgcn_global_load_lds((as1_uint*)src, (as3_uint*)dst, 16, 0, 0);
}
__device__ __forceinline__ unsigned pkh2(float a, float b) {
  union { _Float16 h[2]; unsigned u; } v;
  v.h[0] = (_Float16)a; v.h[1] = (_Float16)b; return v.u;
}

// hi/lo bf16 split of 8 f32 via v_cvt_pk_bf16_f32 (RNE, == f2bf bit pattern)
__device__ __forceinline__ void cvt_hilo8(const f32x4 x0, const f32x4 x1,
                                          short8* hi, short8* lo) {
  union { unsigned u[4]; short8 s; } H, L;
  float f[8];
#pragma unroll
  for (int j = 0; j < 4; ++j) { f[j] = x0[j]; f[4 + j] = x1[j]; }
#pragma unroll
  for (int k = 0; k < 4; ++k) {
    unsigned hk;
    asm("v_cvt_pk_bf16_f32 %0, %1, %2" : "=v"(hk) : "v"(f[2 * k]), "v"(f[2 * k + 1]));
    H.u[k] = hk;
    union { unsigned u; float fl; } h0, h1;
    h0.u = hk << 16;
    h1.u = hk & 0xffff0000u;
    float d0 = f[2 * k] - h0.fl;
    float d1 = f[2 * k + 1] - h1.fl;
    unsigned lk;
    asm("v_cvt_pk_bf16_f32 %0, %1, %2" : "=v"(lk) : "v"(d0), "v"(d1));
    L.u[k] = lk;
  }
  *hi = H.s;
  *lo = L.s;
}

// K0: u fp32 [n][128][256] -> u_hi,u_lo bf16 row-major + uT f16 [n][256][128]
__global__ __launch_bounds__(256) void k0_prep_u(const float* __restrict__ u,
    unsigned short* __restrict__ u_hi, unsigned short* __restrict__ u_lo,
    _Float16* __restrict__ uT16) {
  int n = blockIdx.y, dc = blockIdx.x, t = threadIdx.x;
  const float* un = u + (size_t)n * JQ * DEN;
  unsigned short* uhn = u_hi + (size_t)n * JQ * DEN;
  unsigned short* uln = u_lo + (size_t)n * JQ * DEN;
  __shared__ float lds[JQ * 65];
  for (int i = t; i < JQ * 64; i += 256) {
    int q = i >> 6, dl = i & 63;
    int idx = q * DEN + dc * 64 + dl;
    float f = un[idx];
    unsigned short hi = f2bf(f);
    uhn[idx] = hi;
    uln[idx] = f2bf(f - bf2f(hi));
    lds[q * 65 + dl] = f;
  }
  __syncthreads();
  _Float16* utn = uT16 + (size_t)n * DEN * JQ;
  for (int i = t; i < 64 * JQ; i += 256) {
    int dl = i >> 7, q = i & 127;
    utn[(size_t)(dc * 64 + dl) * JQ + q] = (_Float16)lds[q * 65 + dl];
  }
}

// K1: swapped-operand attention; transposed full-line-NT epilogue; exact vmcnt.
__global__ __launch_bounds__(256, 3) void k1_attn(
    const float* __restrict__ h, const unsigned short* __restrict__ u_hi,
    const unsigned short* __restrict__ u_lo, const _Float16* __restrict__ uT16,
    float* __restrict__ out, float* __restrict__ partM,
    float* __restrict__ partE, float* __restrict__ partV) {
  __shared__ __align__(16) unsigned char SA[32768];  // QK dbuf -> p-arena
  __shared__ __align__(16) unsigned char SB[16384];  // uT chunk / transpose scratch
  __shared__ float pvred[4][4][64];                  // [wave][chunk][col] h~ partials
  __shared__ float emvb[128];                        // exp(m_x - Mblk) per block row
  __shared__ float redM[4], redE[4];

  const int n = blockIdx.x, xb = blockIdx.y;
  const int tid = threadIdx.x;
  const int wave = tid >> 6, lane = tid & 63;
  const int l15 = lane & 15, lq = lane >> 4;
  const int rowbase = xb * 128 + wave * 32;

  const char* uhB = (const char*)(u_hi + (size_t)n * JQ * DEN);
  const char* ulB = (const char*)(u_lo + (size_t)n * JQ * DEN);
  const char* uTB = (const char*)(uT16 + (size_t)n * DEN * JQ);
  const float* hr0 = h + (size_t)(n * JX + rowbase + l15) * DEN;
  const float* hr1 = hr0 + (size_t)16 * DEN;

#define STAGE_QK(BUF, C)                                                     \
  {                                                                          \
    _Pragma("unroll")                                                        \
    for (int rr = 0; rr < 4; ++rr) {                                         \
      int L = rr * 4096 + tid * 16;                                          \
      int row = L >> 7;                                                      \
      int sb = ((L >> 4) & 7) ^ (row & 7);                                   \
      const char* s = (sb & 4) ? ulB : uhB;                                  \
      gload_lds16(s + (size_t)row * 512 + (C) * 64 + (sb & 3) * 16,          \
                  &SA[(BUF) * 16384 + L]);                                   \
    }                                                                        \
  }

  f32x4 acc[2][8];
#pragma unroll
  for (int t = 0; t < 2; ++t)
#pragma unroll
    for (int q = 0; q < 8; ++q) acc[t][q] = (f32x4)(0.f);

  STAGE_QK(0, 0);
  f32x4 hn[2][2];
  hn[0][0] = *(const f32x4*)(hr0 + lq * 8);
  hn[0][1] = *(const f32x4*)(hr0 + lq * 8 + 4);
  hn[1][0] = *(const f32x4*)(hr1 + lq * 8);
  hn[1][1] = *(const f32x4*)(hr1 + lq * 8 + 4);
  // exact count: retire only the 4 stage loads (oldest); h loads stay in flight
  asm volatile("s_waitcnt vmcnt(8)" ::: "memory");
  __builtin_amdgcn_s_barrier();
  __builtin_amdgcn_sched_barrier(0);

#pragma unroll
  for (int c = 0; c < 8; ++c) {
    const int b = c & 1;
    if (c < 7) STAGE_QK(b ^ 1, c + 1);
    f32x4 hc[2][2];
#pragma unroll
    for (int t = 0; t < 2; ++t) { hc[t][0] = hn[t][0]; hc[t][1] = hn[t][1]; }
    if (c < 7) {
      hn[0][0] = *(const f32x4*)(hr0 + (c + 1) * 32 + lq * 8);
      hn[0][1] = *(const f32x4*)(hr0 + (c + 1) * 32 + lq * 8 + 4);
      hn[1][0] = *(const f32x4*)(hr1 + (c + 1) * 32 + lq * 8);
      hn[1][1] = *(const f32x4*)(hr1 + (c + 1) * 32 + lq * 8 + 4);
    }
    short8 bhi[2], blo[2];
#pragma unroll
    for (int t = 0; t < 2; ++t) cvt_hilo8(hc[t][0], hc[t][1], &bhi[t], &blo[t]);
    __builtin_amdgcn_s_setprio(1);
#pragma unroll
    for (int qt = 0; qt < 8; ++qt) {
      int row = qt * 16 + l15;
      const short8 uhf = *(const short8*)(&SA[b * 16384 + row * 128 + ((lq ^ (row & 7)) << 4)]);
      const short8 ulf = *(const short8*)(&SA[b * 16384 + row * 128 + (((4 | lq) ^ (row & 7)) << 4)]);
      acc[0][qt] = __builtin_amdgcn_mfma_f32_16x16x32_bf16(ulf, bhi[0], acc[0][qt], 0, 0, 0);
      acc[0][qt] = __builtin_amdgcn_mfma_f32_16x16x32_bf16(uhf, blo[0], acc[0][qt], 0, 0, 0);
      acc[0][qt] = __builtin_amdgcn_mfma_f32_16x16x32_bf16(uhf, bhi[0], acc[0][qt], 0, 0, 0);
      acc[1][qt] = __builtin_amdgcn_mfma_f32_16x16x32_bf16(ulf, bhi[1], acc[1][qt], 0, 0, 0);
      acc[1][qt] = __builtin_amdgcn_mfma_f32_16x16x32_bf16(uhf, blo[1], acc[1][qt], 0, 0, 0);
      acc[1][qt] = __builtin_amdgcn_mfma_f32_16x16x32_bf16(uhf, bhi[1], acc[1][qt], 0, 0, 0);
    }
    __builtin_amdgcn_s_setprio(0);
    if (c < 7) {
      asm volatile("s_waitcnt vmcnt(8)" ::: "memory");
      __builtin_amdgcn_s_barrier();
      __builtin_amdgcn_sched_barrier(0);
    }
  }

  // stage uT chunk 0 (drained at the redM __syncthreads below)
  {
#pragma unroll
    for (int rr = 0; rr < 4; ++rr) {
      int L = rr * 4096 + tid * 16;
      int row = L >> 8;
      int cb = ((L >> 4) & 15) ^ (row & 7);
      gload_lds16(uTB + (size_t)(row)*256 + cb * 16, &SB[L]);
    }
  }

  // softmax over q (x = l15 lane-local, replicated across lq)
  float mvt[2], rinv[2];
#pragma unroll
  for (int t = 0; t < 2; ++t) {
    float mv = acc[t][0][0];
#pragma unroll
    for (int qt = 0; qt < 8; ++qt)
#pragma unroll
      for (int r = 0; r < 4; ++r) mv = fmaxf(mv, acc[t][qt][r]);
    mv = fmaxf(mv, __shfl_xor(mv, 16));
    mv = fmaxf(mv, __shfl_xor(mv, 32));
    float s = 0.f;
#pragma unroll
    for (int qt = 0; qt < 8; ++qt)
#pragma unroll
      for (int r = 0; r < 4; ++r) {
        float p = __expf(acc[t][qt][r] - mv);
        acc[t][qt][r] = p;
        s += p;
      }
    s += __shfl_xor(s, 16);
    s += __shfl_xor(s, 32);
    mvt[t] = mv;
    rinv[t] = 1.f / s;
  }

  float wmax = fmaxf(mvt[0], mvt[1]);
  wmax = fmaxf(wmax, __shfl_xor(wmax, 1));
  wmax = fmaxf(wmax, __shfl_xor(wmax, 2));
  wmax = fmaxf(wmax, __shfl_xor(wmax, 4));
  wmax = fmaxf(wmax, __shfl_xor(wmax, 8));
  if (lane == 0) redM[wave] = wmax;
  __syncthreads();  // redM visible; SB chunk 0 drained; SA safe to reuse
  const float Mblk = fmaxf(fmaxf(redM[0], redM[1]), fmaxf(redM[2], redM[3]));
  const float w0 = __expf(mvt[0] - Mblk);
  const float w1 = __expf(mvt[1] - Mblk);
  if (lq == 0) {
    emvb[wave * 32 + l15] = w0;
    emvb[wave * 32 + 16 + l15] = w1;
  }
  float es = w0 + w1;
  es += __shfl_xor(es, 1);
  es += __shfl_xor(es, 2);
  es += __shfl_xor(es, 4);
  es += __shfl_xor(es, 8);
  if (lane == 0) redE[wave] = es;

  // pack p (unnormalized, joint-t) into per-wave arena in SA
  char* pw = (char*)SA + wave * 8192;
  const int swz = (l15 & 7) << 4;
#pragma unroll
  for (int t = 0; t < 2; ++t)
#pragma unroll
    for (int qt = 0; qt < 8; ++qt) {
      union { unsigned u2[2]; uint2 u; } pk;
      pk.u2[0] = pkh2(acc[t][qt][0], acc[t][qt][1]);
      pk.u2[1] = pkh2(acc[t][qt][2], acc[t][qt][3]);
      *(uint2*)(pw + (t * 16 + l15) * 256 + ((32 * qt + 8 * lq) ^ swz)) = pk.u;
    }

  // prefetch uT regs for chunk 1 (wave-local slice mapping)
  f32x4 sbreg[4];
#pragma unroll
  for (int rr = 0; rr < 4; ++rr) {
    int L = wave * 4096 + rr * 1024 + lane * 16;
    int row = L >> 8;
    int cb = ((L >> 4) & 15) ^ (row & 7);
    sbreg[rr] = *(const f32x4*)(uTB + (size_t)(64 + row) * 256 + cb * 16);
  }

  char* myscr = (char*)SB + wave * 4096;  // per-wave transpose scratch (4KB)

  // PV + transposed epilogue: 4 chunks of 64 d-cols; 2 barriers/chunk
#pragma unroll
  for (int c = 0; c < 4; ++c) {
    f32x4 vacc[2][4];
#pragma unroll
    for (int t = 0; t < 2; ++t)
#pragma unroll
      for (int dt = 0; dt < 4; ++dt) vacc[t][dt] = (f32x4)(0.f);
    __builtin_amdgcn_s_setprio(1);
#pragma unroll
    for (int ks = 0; ks < 4; ++ks) {
      f16x8 pf[2];
#pragma unroll
      for (int t = 0; t < 2; ++t)
        pf[t] = *(const f16x8*)(pw + (t * 16 + l15) * 256 + ((64 * ks + 16 * lq) ^ swz));
#pragma unroll
      for (int dt = 0; dt < 4; ++dt) {
        int row = dt * 16 + l15;
        const f16x8 Af = *(const f16x8*)(&SB[row * 256 + (((4 * ks + lq) ^ (row & 7)) << 4)]);
        vacc[0][dt] = __builtin_amdgcn_mfma_f32_16x16x32_f16(Af, pf[0], vacc[0][dt], 0, 0, 0);
        vacc[1][dt] = __builtin_amdgcn_mfma_f32_16x16x32_f16(Af, pf[1], vacc[1][dt], 0, 0, 0);
      }
    }
    __builtin_amdgcn_s_setprio(0);

    // early-issue epilogue h loads (LDS-independent; ride through barrier1)
    f32x4 hvv[2][4];
#pragma unroll
    for (int t = 0; t < 2; ++t)
#pragma unroll
      for (int i = 0; i < 4; ++i) {
        int rl = i * 4 + lq;
        hvv[t][i] = *(const f32x4*)(h + (size_t)(n * JX + rowbase + t * 16 + rl) * DEN +
                                    c * 64 + l15 * 4);
      }

    // barrier1: all waves done reading SB chunk c -> slices become scratch
    asm volatile("s_waitcnt lgkmcnt(0)" ::: "memory");
    __builtin_amdgcn_s_barrier();
    __builtin_amdgcn_sched_barrier(0);

    f32x4 pacc = (f32x4)(0.f);
#pragma unroll
    for (int t = 0; t < 2; ++t) {
      // wave-private transpose: write 16 rows x 64 cols (normalized), XOR-swz
#pragma unroll
      for (int dt = 0; dt < 4; ++dt) {
        f32x4 v = vacc[t][dt] * rinv[t];
        *(f32x4*)(myscr + l15 * 256 + (((dt * 4 + lq) ^ l15) << 4)) = v;
      }
      asm volatile("s_waitcnt lgkmcnt(0)" ::: "memory");
      __builtin_amdgcn_sched_barrier(0);
      // row-major readback + 256B full-line NT stores (4 rows/instr x 256B)
      f32x4 utv[4];
#pragma unroll
      for (int i = 0; i < 4; ++i) {
        int rl = i * 4 + lq;
        utv[i] = *(const f32x4*)(myscr + rl * 256 + ((l15 ^ rl) << 4));
      }
#pragma unroll
      for (int i = 0; i < 4; ++i) {
        int rl = i * 4 + lq;
        float* op = out + (size_t)(n * JX + rowbase + t * 16 + rl) * 1024 + c * 64 + l15 * 4;
        __builtin_nontemporal_store(hvv[t][i], (f32x4*)op);
        __builtin_nontemporal_store(utv[i], (f32x4*)(op + 256));
        __builtin_nontemporal_store(hvv[t][i] * utv[i], (f32x4*)(op + 512));
        pacc += hvv[t][i] * emvb[wave * 32 + t * 16 + rl];
      }
      asm volatile("s_waitcnt lgkmcnt(0)" ::: "memory");
      __builtin_amdgcn_sched_barrier(0);
    }

    // lq-reduce pacc in-wave, store to wave-private pvred slot (no barrier)
#pragma unroll
    for (int j = 0; j < 4; ++j) {
      pacc[j] += __shfl_xor(pacc[j], 16);
      pacc[j] += __shfl_xor(pacc[j], 32);
    }
    if (lq == 0) *(f32x4*)(&pvred[wave][c][l15 * 4]) = pacc;

    if (c < 3) {
      // refill OWN slice of SB with pre-loaded chunk c+1, prefetch c+2
#pragma unroll
      for (int rr = 0; rr < 4; ++rr)
        *(f32x4*)(&SB[wave * 4096 + rr * 1024 + lane * 16]) = sbreg[rr];
      if (c < 2) {
#pragma unroll
        for (int rr = 0; rr < 4; ++rr) {
          int L = wave * 4096 + rr * 1024 + lane * 16;
          int row = L >> 8;
          int cb = ((L >> 4) & 15) ^ (row & 7);
          sbreg[rr] = *(const f32x4*)(uTB + (size_t)((c + 2) * 64 + row) * 256 + cb * 16);
        }
      }
      // barrier2: all slices refilled before next chunk's MFMAs
      asm volatile("s_waitcnt lgkmcnt(0)" ::: "memory");
      __builtin_amdgcn_s_barrier();
      __builtin_amdgcn_sched_barrier(0);
    }
  }

  __syncthreads();  // pvred + redE visible
  {
    int cc = tid >> 6, col = tid & 63;
    float s = pvred[0][cc][col] + pvred[1][cc][col] +
              pvred[2][cc][col] + pvred[3][cc][col];
    partV[((size_t)(n * 16 + xb)) * 256 + tid] = s;
  }
  if (tid == 0) {
    partM[n * 16 + xb] = Mblk;
    partE[n * 16 + xb] = redE[0] + redE[1] + redE[2] + redE[3];
  }
#undef STAGE_QK
}

// K3: merge block partials (online-softmax weighted), write quarter 4 (NT).
__global__ __launch_bounds__(256) void k3_quarter4(const float* __restrict__ h,
    const float* __restrict__ partM, const float* __restrict__ partE,
    const float* __restrict__ partV, float* __restrict__ out) {
  int n = blockIdx.y, xc = blockIdx.x, t = threadIdx.x;
  __shared__ float sm[16], se[16];
  __shared__ float ht[DEN];
  if (t < 16) { sm[t] = partM[n * 16 + t]; se[t] = partE[n * 16 + t]; }
  __syncthreads();
  float M = sm[0];
#pragma unroll
  for (int c = 1; c < 16; ++c) M = fmaxf(M, sm[c]);
  float den = 0.f, s = 0.f;
#pragma unroll
  for (int c = 0; c < 16; ++c) {
    float fc = __expf(sm[c] - M);
    den += fc * se[c];
    s += fc * partV[((size_t)(n * 16 + c)) * 256 + t];
  }
  ht[t] = s / den;
  __syncthreads();
  int wave = t >> 6, c4 = t & 63;
  f32x4 htv = *(const f32x4*)(ht + c4 * 4);
#pragma unroll
  for (int i = 0; i < 8; ++i) {
    int row = xc * 32 + i * 4 + wave;
    f32x4 hv = *(const f32x4*)(h + (size_t)(n * JX + row) * DEN + c4 * 4);
    f32x4 hh = hv * htv;
    __builtin_nontemporal_store(hh,
        (f32x4*)(out + (size_t)(n * JX + row) * 1024 + 768 + c4 * 4));
  }
}

extern "C" void kernel_launch(void* const* d_in, const int* in_sizes, int n_in,
                              void* d_out, int out_size, void* d_ws, size_t ws_size,
                              hipStream_t stream) {
  const float* h = (const float*)d_in[0];
  const float* u = (const float*)d_in[1];
  float* out = (float*)d_out;
  char* ws = (char*)d_ws;

  size_t off = 0;
  unsigned short* u_hi = (unsigned short*)(ws + off); off += (size_t)NB * JQ * DEN * 2;
  unsigned short* u_lo = (unsigned short*)(ws + off); off += (size_t)NB * JQ * DEN * 2;
  _Float16* uT16 = (_Float16*)(ws + off); off += (size_t)NB * DEN * JQ * 2;
  float* partM = (float*)(ws + off); off += (size_t)NB * 16 * 4;
  float* partE = (float*)(ws + off); off += (size_t)NB * 16 * 4;
  float* partV = (float*)(ws + off); off += (size_t)NB * 16 * DEN * 4;

  hipLaunchKernelGGL(k0_prep_u, dim3(4, NB), dim3(256), 0, stream, u, u_hi, u_lo, uT16);
  hipLaunchKernelGGL(k1_attn, dim3(NB, JX / 128), dim3(256), 0, stream,
                     h, u_hi, u_lo, uT16, out, partM, partE, partV);
  hipLaunchKernelGGL(k3_quarter4, dim3(64, NB), dim3(256), 0, stream,
                     h, partM, partE, partV, out);
}